// Round 1
// baseline (1516.156 us; speedup 1.0000x reference)
//
#include <hip/hip_runtime.h>
#include <hip/hip_bf16.h>

// Problem constants
#define BB 64
#define NN 2000
#define GG 128
#define HH 128
#define NHEAD 8
#define HD 16

__device__ __forceinline__ void fma8x8(const float4& a0, const float4& a1,
                                       const float4& b0, const float4& b1,
                                       float acc[8][8]) {
    const float av[8] = {a0.x, a0.y, a0.z, a0.w, a1.x, a1.y, a1.z, a1.w};
    const float bv[8] = {b0.x, b0.y, b0.z, b0.w, b1.x, b1.y, b1.z, b1.w};
#pragma unroll
    for (int i = 0; i < 8; ++i)
#pragma unroll
        for (int k = 0; k < 8; ++k) acc[i][k] += av[i] * bv[k];
}

// ---- K1: transpose 7 weight matrices (128x128): WT[m][j][c] = W_m[c][j] ----
__global__ void k_wt(const float* w0, const float* w1, const float* w2,
                     const float* w3, const float* w4, const float* w5,
                     const float* w6, float* WT) {
    __shared__ float t[128 * 129];
    int m = blockIdx.x;
    const float* src = (m == 0) ? w0 : (m == 1) ? w1 : (m == 2) ? w2 :
                       (m == 3) ? w3 : (m == 4) ? w4 : (m == 5) ? w5 : w6;
    for (int e = threadIdx.x; e < 16384; e += 256) {
        int c = e >> 7, j = e & 127;
        t[c * 129 + j] = src[e];
    }
    __syncthreads();
    for (int e = threadIdx.x; e < 16384; e += 256) {
        int j = e >> 7, c = e & 127;
        WT[m * 16384 + e] = t[c * 129 + j];
    }
}

// ---- K2: mask -> bitmask. bits[(b*G+g)*32 + w] bit l = keep(n = w*64+l) ----
__global__ void k_maskbits(const float* mask, unsigned long long* bits) {
    int bg = blockIdx.x;
    int lane = threadIdx.x & 63;
    int wv = threadIdx.x >> 6;
    for (int w = wv; w < 32; w += 4) {
        int n = w * 64 + lane;
        bool keep = false;
        if (n < NN) keep = (mask[(size_t)bg * NN + n] == 0.0f);
        unsigned long long bal = __ballot(keep);
        if (lane == 0) bits[bg * 32 + w] = bal;
    }
}

// ---- K3: partial column sums of embeddings (for graph mean) ----
__global__ void k_gsum(const float* emb, float* gpart) {
    int ck = blockIdx.x, b = blockIdx.y, c = threadIdx.x;
    const float* p = emb + ((size_t)b * NN + ck * 125) * HH + c;
    float s = 0.0f;
#pragma unroll 5
    for (int r = 0; r < 125; ++r) s += p[(size_t)r * HH];
    gpart[ck * 8192 + b * 128 + c] = s;
}

// ---- K4: qbase[b][c] = graph@WqgT + src@WqsT + tgt@WqtT ----
__global__ void k_qbase(const float* emb, const int* srcn, const int* tgtn,
                        const float* gpart, const float* WT, float* qbase) {
    int b = blockIdx.x, c = threadIdx.x;
    __shared__ float ge[128], se[128], te[128];
    float s = 0.0f;
#pragma unroll
    for (int t = 0; t < 16; ++t) s += gpart[t * 8192 + b * 128 + c];
    ge[c] = s * (1.0f / 2000.0f);
    se[c] = emb[((size_t)b * NN + srcn[b]) * HH + c];
    te[c] = emb[((size_t)b * NN + tgtn[b]) * HH + c];
    __syncthreads();
    const float* Wg = WT;
    const float* Ws = WT + 16384;
    const float* Wt2 = WT + 32768;
    float acc = 0.0f;
#pragma unroll 4
    for (int j = 0; j < 128; ++j) {
        acc += ge[j] * Wg[j * 128 + c] + se[j] * Ws[j * 128 + c] + te[j] * Wt2[j * 128 + c];
    }
    qbase[b * 128 + c] = acc;
}

// ---- K5: Q[b][g][c] = 0.25*(qbase[b][c] + lastemb[b][g]@WqlT) ----
__global__ void k_qlast(const float* emb, const int* lastn, const float* WT,
                        const float* qbase, float* Q) {
    int b = blockIdx.x;
    int tid = threadIdx.x, xq = tid & 15, yq = tid >> 4;
    __shared__ float Bl[128 * 132];
    for (int e = tid; e < 16384; e += 256) {
        int g = e >> 7, j = e & 127;
        Bl[j * 132 + g] = emb[((size_t)b * NN + lastn[b * 128 + g]) * HH + j];
    }
    __syncthreads();
    const float* Wql = WT + 3 * 16384;
    float acc[8][8] = {};  // y = c (from Wql), x = g (from Bl)
#pragma unroll 4
    for (int j = 0; j < 128; ++j) {
        const float4* Ar = (const float4*)(Wql + j * 128);
        float4 a0 = Ar[yq], a1 = Ar[16 + yq];
        const float4* Br = (const float4*)(Bl + j * 132);
        float4 b0 = Br[xq], b1 = Br[16 + xq];
        fma8x8(a0, a1, b0, b1, acc);
    }
    float4 qb0 = *(const float4*)(qbase + b * 128 + 4 * yq);
    float4 qb1 = *(const float4*)(qbase + b * 128 + 64 + 4 * yq);
#pragma unroll
    for (int k = 0; k < 8; ++k) {
        int g = (k < 4) ? (4 * xq + k) : (64 + 4 * xq + (k - 4));
        float* orow = Q + ((size_t)b * 128 + g) * 128;
        float4 v0 = make_float4((acc[0][k] + qb0.x) * 0.25f, (acc[1][k] + qb0.y) * 0.25f,
                                (acc[2][k] + qb0.z) * 0.25f, (acc[3][k] + qb0.w) * 0.25f);
        float4 v1 = make_float4((acc[4][k] + qb1.x) * 0.25f, (acc[5][k] + qb1.y) * 0.25f,
                                (acc[6][k] + qb1.z) * 0.25f, (acc[7][k] + qb1.w) * 0.25f);
        *(float4*)(orow + 4 * yq) = v0;
        *(float4*)(orow + 64 + 4 * yq) = v1;
    }
}

// ---- K6: K/V projections -> Kt[b][c][n], Vt[b][c][n] ----
__global__ void k_kv(const float* emb, const float* WT, float* Kt, float* Vt) {
    int nt = blockIdx.x, b = blockIdx.y;
    int tid = threadIdx.x, xq = tid & 15, yq = tid >> 4;
    int n0 = nt * 128;
    __shared__ float Al[64 * 132];
    __shared__ float Bl[64 * 132];
    for (int gemm = 0; gemm < 2; ++gemm) {
        const float* Wsrc = WT + (4 + gemm) * 16384;
        float* out = gemm ? Vt : Kt;
        float acc[8][8] = {};
        for (int jh = 0; jh < 2; ++jh) {
            __syncthreads();
            for (int e = tid; e < 8192; e += 256) {
                int jl = e >> 7, c = e & 127;
                Al[jl * 132 + c] = Wsrc[(jh * 64 + jl) * 128 + c];
            }
            for (int e = tid; e < 8192; e += 256) {
                int jl = e & 63, r = e >> 6;
                int n = n0 + r;
                Bl[jl * 132 + r] = (n < NN) ? emb[((size_t)b * NN + n) * HH + jh * 64 + jl] : 0.0f;
            }
            __syncthreads();
#pragma unroll 4
            for (int jl = 0; jl < 64; ++jl) {
                const float4* Ar = (const float4*)(Al + jl * 132);
                float4 a0 = Ar[yq], a1 = Ar[16 + yq];
                const float4* Br = (const float4*)(Bl + jl * 132);
                float4 b0 = Br[xq], b1 = Br[16 + xq];
                fma8x8(a0, a1, b0, b1, acc);
            }
        }
#pragma unroll
        for (int i = 0; i < 8; ++i) {
            int c = (i < 4) ? (4 * yq + i) : (64 + 4 * yq + (i - 4));
            float* orow = out + ((size_t)b * 128 + c) * NN + n0;
            int nA = 4 * xq;
            if (n0 + nA + 3 < NN)
                *(float4*)(orow + nA) = make_float4(acc[i][0], acc[i][1], acc[i][2], acc[i][3]);
            int nB = 64 + 4 * xq;
            if (n0 + nB + 3 < NN)
                *(float4*)(orow + nB) = make_float4(acc[i][4], acc[i][5], acc[i][6], acc[i][7]);
        }
    }
}

// ---- K7: flash attention per (b,h), no-max softmax via bitmask ----
__global__ void k_flash(const float* Kt, const float* Vt, const float* Q,
                        const unsigned long long* bits, float* MHt) {
    int bid = blockIdx.x;
    int b = bid >> 3, h = bid & 7;
    int tid = threadIdx.x, gq = tid >> 3, nq = tid & 7;
    __shared__ float KT[16 * 64];
    __shared__ float VT[16 * 64];
    float q[4][16];
#pragma unroll
    for (int i = 0; i < 4; ++i) {
        const float4* Qr = (const float4*)(Q + ((size_t)b * 128 + gq * 4 + i) * 128 + h * 16);
        float4 t0 = Qr[0], t1 = Qr[1], t2 = Qr[2], t3 = Qr[3];
        q[i][0] = t0.x; q[i][1] = t0.y; q[i][2] = t0.z; q[i][3] = t0.w;
        q[i][4] = t1.x; q[i][5] = t1.y; q[i][6] = t1.z; q[i][7] = t1.w;
        q[i][8] = t2.x; q[i][9] = t2.y; q[i][10] = t2.z; q[i][11] = t2.w;
        q[i][12] = t3.x; q[i][13] = t3.y; q[i][14] = t3.z; q[i][15] = t3.w;
    }
    float O[4][16] = {};
    float Z[4] = {0.0f, 0.0f, 0.0f, 0.0f};
    const unsigned long long* bb = bits + (size_t)b * 128 * 32;
    const float* Kbase = Kt + ((size_t)b * 128 + h * 16) * NN;
    const float* Vbase = Vt + ((size_t)b * 128 + h * 16) * NN;
    for (int ch = 0; ch < 32; ++ch) {
        int n0 = ch * 64;
        __syncthreads();
        for (int e = tid; e < 1024; e += 256) {
            int d = e >> 6, i2 = e & 63;
            int n = n0 + i2;
            float kv = 0.0f, vv = 0.0f;
            if (n < NN) {
                kv = Kbase[(size_t)d * NN + n];
                vv = Vbase[(size_t)d * NN + n];
            }
            KT[d * 64 + i2] = kv;
            VT[d * 64 + i2] = vv;
        }
        unsigned long long w[4];
#pragma unroll
        for (int i = 0; i < 4; ++i) w[i] = bb[(gq * 4 + i) * 32 + ch];
        __syncthreads();
        float s[4][8] = {};
        const float4* K4 = (const float4*)KT;
#pragma unroll
        for (int d = 0; d < 16; ++d) {
            float4 ka = K4[d * 16 + nq], kb = K4[d * 16 + 8 + nq];
#pragma unroll
            for (int i = 0; i < 4; ++i) {
                float qv = q[i][d];
                s[i][0] += qv * ka.x; s[i][1] += qv * ka.y;
                s[i][2] += qv * ka.z; s[i][3] += qv * ka.w;
                s[i][4] += qv * kb.x; s[i][5] += qv * kb.y;
                s[i][6] += qv * kb.z; s[i][7] += qv * kb.w;
            }
        }
#pragma unroll
        for (int i = 0; i < 4; ++i) {
#pragma unroll
            for (int j = 0; j < 8; ++j) {
                int l = (j < 4) ? (4 * nq + j) : (32 + 4 * nq + (j - 4));
                float e = ((w[i] >> l) & 1ull) ? __expf(s[i][j]) : 0.0f;
                s[i][j] = e;
                Z[i] += e;
            }
        }
        const float4* V4 = (const float4*)VT;
#pragma unroll
        for (int d = 0; d < 16; ++d) {
            float4 va = V4[d * 16 + nq], vb = V4[d * 16 + 8 + nq];
#pragma unroll
            for (int i = 0; i < 4; ++i) {
                O[i][d] += s[i][0] * va.x + s[i][1] * va.y + s[i][2] * va.z + s[i][3] * va.w +
                           s[i][4] * vb.x + s[i][5] * vb.y + s[i][6] * vb.z + s[i][7] * vb.w;
            }
        }
    }
#pragma unroll
    for (int i = 0; i < 4; ++i) {
#pragma unroll
        for (int m = 1; m <= 4; m <<= 1) Z[i] += __shfl_xor(Z[i], m);
#pragma unroll
        for (int d = 0; d < 16; ++d) {
#pragma unroll
            for (int m = 1; m <= 4; m <<= 1) O[i][d] += __shfl_xor(O[i][d], m);
        }
    }
    if (nq == 0) {
#pragma unroll
        for (int i = 0; i < 4; ++i) {
            float inv = 1.0f / Z[i];
            int g = gq * 4 + i;
#pragma unroll
            for (int d = 0; d < 16; ++d) {
                MHt[((size_t)b * 128 + h * 16 + d) * 128 + g] = O[i][d] * inv;
            }
        }
    }
}

// ---- K8: FQt[b][c][g] = (MH[b][g]@WcT + bc)*rsqrt(H) ----
__global__ void k_fq(const float* MHt, const float* WT, const float* bcv, float* FQt) {
    int b = blockIdx.x;
    int tid = threadIdx.x, xq = tid & 15, yq = tid >> 4;
    __shared__ float Bl[128 * 132];
    for (int e = tid; e < 16384; e += 256) {
        int j = e >> 7, g = e & 127;
        Bl[j * 132 + g] = MHt[(size_t)b * 16384 + e];
    }
    __syncthreads();
    const float* Wc = WT + 6 * 16384;
    float acc[8][8] = {};  // y = c, x = g
#pragma unroll 4
    for (int j = 0; j < 128; ++j) {
        const float4* Ar = (const float4*)(Wc + j * 128);
        float4 a0 = Ar[yq], a1 = Ar[16 + yq];
        const float4* Br = (const float4*)(Bl + j * 132);
        float4 b0 = Br[xq], b1 = Br[16 + xq];
        fma8x8(a0, a1, b0, b1, acc);
    }
    float4 bc0 = *(const float4*)(bcv + 4 * yq);
    float4 bc1 = *(const float4*)(bcv + 64 + 4 * yq);
    const float bcv8[8] = {bc0.x, bc0.y, bc0.z, bc0.w, bc1.x, bc1.y, bc1.z, bc1.w};
    const float sc = 0.08838834764831845f;  // 1/sqrt(128)
#pragma unroll
    for (int i = 0; i < 8; ++i) {
        int c = (i < 4) ? (4 * yq + i) : (64 + 4 * yq + (i - 4));
        float bci = bcv8[i];
        float* orow = FQt + ((size_t)b * 128 + c) * 128;
        *(float4*)(orow + 4 * xq) =
            make_float4((acc[i][0] + bci) * sc, (acc[i][1] + bci) * sc,
                        (acc[i][2] + bci) * sc, (acc[i][3] + bci) * sc);
        *(float4*)(orow + 64 + 4 * xq) =
            make_float4((acc[i][4] + bci) * sc, (acc[i][5] + bci) * sc,
                        (acc[i][6] + bci) * sc, (acc[i][7] + bci) * sc);
    }
}

// ---- K9: logits GEMM + tanh clip + masked exp; writes unnormalized p + row partial sums ----
__global__ void k_logits(const float* emb, const float* FQt, const unsigned long long* bits,
                         float* out, float* Zp) {
    int nt = blockIdx.x, b = blockIdx.y;
    int tid = threadIdx.x, xq = tid & 15, yq = tid >> 4;
    int n0 = nt * 128;
    __shared__ float Al[64 * 132];
    __shared__ float Bl[64 * 132];
    float acc[8][8] = {};  // y = g, x = n
    for (int chh = 0; chh < 2; ++chh) {
        __syncthreads();
        for (int e = tid; e < 8192; e += 256) {
            int jl = e >> 7, g = e & 127;
            Al[jl * 132 + g] = FQt[((size_t)b * 128 + chh * 64 + jl) * 128 + g];
        }
        for (int e = tid; e < 8192; e += 256) {
            int jl = e & 63, r = e >> 6;
            int n = n0 + r;
            Bl[jl * 132 + r] = (n < NN) ? emb[((size_t)b * NN + n) * HH + chh * 64 + jl] : 0.0f;
        }
        __syncthreads();
#pragma unroll 4
        for (int jl = 0; jl < 64; ++jl) {
            const float4* Ar = (const float4*)(Al + jl * 132);
            float4 a0 = Ar[yq], a1 = Ar[16 + yq];
            const float4* Br = (const float4*)(Bl + jl * 132);
            float4 b0 = Br[xq], b1 = Br[16 + xq];
            fma8x8(a0, a1, b0, b1, acc);
        }
    }
    float psum[8];
    const unsigned long long* bb = bits + (size_t)b * 128 * 32;
#pragma unroll
    for (int i = 0; i < 8; ++i) {
        int g = (i < 4) ? (4 * yq + i) : (64 + 4 * yq + (i - 4));
        unsigned long long w0 = bb[g * 32 + nt * 2];
        unsigned long long w1 = bb[g * 32 + nt * 2 + 1];
        float* orow = out + ((size_t)b * 128 + g) * NN + n0;
        float ps = 0.0f;
        float pv[8];
#pragma unroll
        for (int k = 0; k < 8; ++k) {
            int nl = (k < 4) ? (4 * xq + k) : (64 + 4 * xq + (k - 4));
            unsigned long long w = (nl < 64) ? w0 : w1;
            int sh = nl & 63;
            float l = acc[i][k];
            float e2 = __expf(2.0f * l);
            float th = 1.0f - 2.0f / (e2 + 1.0f);
            float p = ((w >> sh) & 1ull) ? __expf(10.0f * th) : 0.0f;
            pv[k] = p;
            ps += p;
        }
        if (n0 + 4 * xq + 3 < NN)
            *(float4*)(orow + 4 * xq) = make_float4(pv[0], pv[1], pv[2], pv[3]);
        if (n0 + 64 + 4 * xq + 3 < NN)
            *(float4*)(orow + 64 + 4 * xq) = make_float4(pv[4], pv[5], pv[6], pv[7]);
        psum[i] = ps;
    }
#pragma unroll
    for (int i = 0; i < 8; ++i) {
#pragma unroll
        for (int m = 1; m <= 8; m <<= 1) psum[i] += __shfl_xor(psum[i], m);
    }
    if (xq == 0) {
#pragma unroll
        for (int i = 0; i < 8; ++i) {
            int g = (i < 4) ? (4 * yq + i) : (64 + 4 * yq + (i - 4));
            Zp[nt * 8192 + b * 128 + g] = psum[i];
        }
    }
}

// ---- K10: normalize probs ----
__global__ void k_norm(const float* Zp, float* out) {
    int bg = blockIdx.x;
    __shared__ float invs;
    if (threadIdx.x == 0) {
        float s = 0.0f;
#pragma unroll
        for (int t = 0; t < 16; ++t) s += Zp[t * 8192 + bg];
        invs = 1.0f / s;
    }
    __syncthreads();
    float inv = invs;
    for (int n = threadIdx.x; n < NN; n += 256) out[(size_t)bg * NN + n] *= inv;
}

extern "C" void kernel_launch(void* const* d_in, const int* in_sizes, int n_in,
                              void* d_out, int out_size, void* d_ws, size_t ws_size,
                              hipStream_t stream) {
    const float* emb = (const float*)d_in[0];
    const float* mask = (const float*)d_in[1];
    const float* Wqg = (const float*)d_in[2];
    const float* Wqs = (const float*)d_in[3];
    const float* Wqt = (const float*)d_in[4];
    const float* Wql = (const float*)d_in[5];
    const float* Wk = (const float*)d_in[6];
    const float* Wv = (const float*)d_in[7];
    const float* Wc = (const float*)d_in[8];
    const float* bc = (const float*)d_in[9];
    const int* srcn = (const int*)d_in[10];
    const int* tgtn = (const int*)d_in[11];
    const int* lastn = (const int*)d_in[12];
    float* out = (float*)d_out;

    float* ws = (float*)d_ws;
    float* WT = ws;                         // 7*16384 = 114688
    float* gpart = ws + 114688;             // 131072
    float* qbase = ws + 245760;             // 8192
    float* Q = ws + 253952;                 // 1048576
    float* MHt = ws + 1302528;              // 1048576
    float* FQt = ws + 2351104;              // 1048576
    float* Zp = ws + 3399680;               // 131072
    float* Kt = ws + 3530752;               // 16384000
    float* Vt = ws + 19914752;              // 16384000
    unsigned long long* bits = (unsigned long long*)((char*)d_ws + (size_t)36298752 * 4);

    k_wt<<<7, 256, 0, stream>>>(Wqg, Wqs, Wqt, Wql, Wk, Wv, Wc, WT);
    k_maskbits<<<8192, 256, 0, stream>>>(mask, bits);
    k_gsum<<<dim3(16, 64), 128, 0, stream>>>(emb, gpart);
    k_kv<<<dim3(16, 64), 256, 0, stream>>>(emb, WT, Kt, Vt);
    k_qbase<<<64, 128, 0, stream>>>(emb, srcn, tgtn, gpart, WT, qbase);
    k_qlast<<<64, 256, 0, stream>>>(emb, lastn, WT, qbase, Q);
    k_flash<<<512, 256, 0, stream>>>(Kt, Vt, Q, bits, MHt);
    k_fq<<<64, 256, 0, stream>>>(MHt, WT, bc, FQt);
    k_logits<<<dim3(16, 64), 256, 0, stream>>>(emb, FQt, bits, out, Zp);
    k_norm<<<8192, 256, 0, stream>>>(Zp, out);
}

// Round 2
// 675.271 us; speedup vs baseline: 2.2453x; 2.2453x over previous
//
#include <hip/hip_runtime.h>
#include <hip/hip_bf16.h>

// Problem constants
#define BB 64
#define NN 2000
#define GG 128
#define HH 128
#define NHEAD 8
#define HD 16

__device__ __forceinline__ void fma8x8(const float4& a0, const float4& a1,
                                       const float4& b0, const float4& b1,
                                       float acc[8][8]) {
    const float av[8] = {a0.x, a0.y, a0.z, a0.w, a1.x, a1.y, a1.z, a1.w};
    const float bv[8] = {b0.x, b0.y, b0.z, b0.w, b1.x, b1.y, b1.z, b1.w};
#pragma unroll
    for (int i = 0; i < 8; ++i)
#pragma unroll
        for (int k = 0; k < 8; ++k) acc[i][k] += av[i] * bv[k];
}

// ---- K1: transpose 7 weight matrices (128x128): WT[m][j][c] = W_m[c][j] ----
__global__ __launch_bounds__(256) void k_wt(const float* w0, const float* w1, const float* w2,
                     const float* w3, const float* w4, const float* w5,
                     const float* w6, float* WT) {
    __shared__ float t[128 * 129];
    int m = blockIdx.x;
    const float* src = (m == 0) ? w0 : (m == 1) ? w1 : (m == 2) ? w2 :
                       (m == 3) ? w3 : (m == 4) ? w4 : (m == 5) ? w5 : w6;
    for (int e = threadIdx.x; e < 16384; e += 256) {
        int c = e >> 7, j = e & 127;
        t[c * 129 + j] = src[e];
    }
    __syncthreads();
    for (int e = threadIdx.x; e < 16384; e += 256) {
        int j = e >> 7, c = e & 127;
        WT[m * 16384 + e] = t[c * 129 + j];
    }
}

// ---- K2: mask -> bitmask. bits[(b*G+g)*32 + w] bit l = keep(n = w*64+l) ----
__global__ __launch_bounds__(256) void k_maskbits(const float* mask, unsigned long long* bits) {
    int bg = blockIdx.x;
    int lane = threadIdx.x & 63;
    int wv = threadIdx.x >> 6;
    for (int w = wv; w < 32; w += 4) {
        int n = w * 64 + lane;
        bool keep = false;
        if (n < NN) keep = (mask[(size_t)bg * NN + n] == 0.0f);
        unsigned long long bal = __ballot(keep);
        if (lane == 0) bits[bg * 32 + w] = bal;
    }
}

// ---- K3: partial column sums of embeddings (for graph mean) ----
__global__ __launch_bounds__(128) void k_gsum(const float* emb, float* gpart) {
    int ck = blockIdx.x, b = blockIdx.y, c = threadIdx.x;
    const float* p = emb + ((size_t)b * NN + ck * 125) * HH + c;
    float s = 0.0f;
#pragma unroll 5
    for (int r = 0; r < 125; ++r) s += p[(size_t)r * HH];
    gpart[ck * 8192 + b * 128 + c] = s;
}

// ---- K4: qbase[b][c] = graph@WqgT + src@WqsT + tgt@WqtT ----
__global__ __launch_bounds__(128) void k_qbase(const float* emb, const int* srcn, const int* tgtn,
                        const float* gpart, const float* WT, float* qbase) {
    int b = blockIdx.x, c = threadIdx.x;
    __shared__ float ge[128], se[128], te[128];
    float s = 0.0f;
#pragma unroll
    for (int t = 0; t < 16; ++t) s += gpart[t * 8192 + b * 128 + c];
    ge[c] = s * (1.0f / 2000.0f);
    se[c] = emb[((size_t)b * NN + srcn[b]) * HH + c];
    te[c] = emb[((size_t)b * NN + tgtn[b]) * HH + c];
    __syncthreads();
    const float* Wg = WT;
    const float* Ws = WT + 16384;
    const float* Wt2 = WT + 32768;
    float acc = 0.0f;
#pragma unroll 4
    for (int j = 0; j < 128; ++j) {
        acc += ge[j] * Wg[j * 128 + c] + se[j] * Ws[j * 128 + c] + te[j] * Wt2[j * 128 + c];
    }
    qbase[b * 128 + c] = acc;
}

// ---- K5: Q[b][g][c] = 0.25*(qbase[b][c] + lastemb[b][g]@WqlT) ----
__global__ __launch_bounds__(256) void k_qlast(const float* emb, const int* lastn, const float* WT,
                        const float* qbase, float* Q) {
    int b = blockIdx.x;
    int tid = threadIdx.x, xq = tid & 15, yq = tid >> 4;
    __shared__ float Bl[128 * 132];
    for (int e = tid; e < 16384; e += 256) {
        int g = e >> 7, j = e & 127;
        Bl[j * 132 + g] = emb[((size_t)b * NN + lastn[b * 128 + g]) * HH + j];
    }
    __syncthreads();
    const float* Wql = WT + 3 * 16384;
    float acc[8][8] = {};  // y = c (from Wql), x = g (from Bl)
#pragma unroll 4
    for (int j = 0; j < 128; ++j) {
        const float4* Ar = (const float4*)(Wql + j * 128);
        float4 a0 = Ar[yq], a1 = Ar[16 + yq];
        const float4* Br = (const float4*)(Bl + j * 132);
        float4 b0 = Br[xq], b1 = Br[16 + xq];
        fma8x8(a0, a1, b0, b1, acc);
    }
    float4 qb0 = *(const float4*)(qbase + b * 128 + 4 * yq);
    float4 qb1 = *(const float4*)(qbase + b * 128 + 64 + 4 * yq);
#pragma unroll
    for (int k = 0; k < 8; ++k) {
        int g = (k < 4) ? (4 * xq + k) : (64 + 4 * xq + (k - 4));
        float* orow = Q + ((size_t)b * 128 + g) * 128;
        float4 v0 = make_float4((acc[0][k] + qb0.x) * 0.25f, (acc[1][k] + qb0.y) * 0.25f,
                                (acc[2][k] + qb0.z) * 0.25f, (acc[3][k] + qb0.w) * 0.25f);
        float4 v1 = make_float4((acc[4][k] + qb1.x) * 0.25f, (acc[5][k] + qb1.y) * 0.25f,
                                (acc[6][k] + qb1.z) * 0.25f, (acc[7][k] + qb1.w) * 0.25f);
        *(float4*)(orow + 4 * yq) = v0;
        *(float4*)(orow + 64 + 4 * yq) = v1;
    }
}

// ---- K6: K/V projections -> Kt[b][c][n], Vt[b][c][n] ----
__global__ __launch_bounds__(256) void k_kv(const float* emb, const float* WT, float* Kt, float* Vt) {
    int nt = blockIdx.x, b = blockIdx.y;
    int tid = threadIdx.x, xq = tid & 15, yq = tid >> 4;
    int n0 = nt * 128;
    __shared__ float Al[64 * 132];
    __shared__ float Bl[64 * 132];
    for (int gemm = 0; gemm < 2; ++gemm) {
        const float* Wsrc = WT + (4 + gemm) * 16384;
        float* out = gemm ? Vt : Kt;
        float acc[8][8] = {};
        for (int jh = 0; jh < 2; ++jh) {
            __syncthreads();
            for (int e = tid; e < 8192; e += 256) {
                int jl = e >> 7, c = e & 127;
                Al[jl * 132 + c] = Wsrc[(jh * 64 + jl) * 128 + c];
            }
            for (int e = tid; e < 8192; e += 256) {
                int jl = e & 63, r = e >> 6;
                int n = n0 + r;
                Bl[jl * 132 + r] = (n < NN) ? emb[((size_t)b * NN + n) * HH + jh * 64 + jl] : 0.0f;
            }
            __syncthreads();
#pragma unroll 4
            for (int jl = 0; jl < 64; ++jl) {
                const float4* Ar = (const float4*)(Al + jl * 132);
                float4 a0 = Ar[yq], a1 = Ar[16 + yq];
                const float4* Br = (const float4*)(Bl + jl * 132);
                float4 b0 = Br[xq], b1 = Br[16 + xq];
                fma8x8(a0, a1, b0, b1, acc);
            }
        }
#pragma unroll
        for (int i = 0; i < 8; ++i) {
            int c = (i < 4) ? (4 * yq + i) : (64 + 4 * yq + (i - 4));
            float* orow = out + ((size_t)b * 128 + c) * NN + n0;
            int nA = 4 * xq;
            if (n0 + nA + 3 < NN)
                *(float4*)(orow + nA) = make_float4(acc[i][0], acc[i][1], acc[i][2], acc[i][3]);
            int nB = 64 + 4 * xq;
            if (n0 + nB + 3 < NN)
                *(float4*)(orow + nB) = make_float4(acc[i][4], acc[i][5], acc[i][6], acc[i][7]);
        }
    }
}

// ---- K7: flash attention per (b,h), no-max softmax via bitmask ----
__global__ __launch_bounds__(256) void k_flash(const float* Kt, const float* Vt, const float* Q,
                        const unsigned long long* bits, float* MHt) {
    int bid = blockIdx.x;
    int b = bid >> 3, h = bid & 7;
    int tid = threadIdx.x, gq = tid >> 3, nq = tid & 7;
    __shared__ float KT[16 * 64];
    __shared__ float VT[16 * 64];
    float q[4][16];
#pragma unroll
    for (int i = 0; i < 4; ++i) {
        const float4* Qr = (const float4*)(Q + ((size_t)b * 128 + gq * 4 + i) * 128 + h * 16);
        float4 t0 = Qr[0], t1 = Qr[1], t2 = Qr[2], t3 = Qr[3];
        q[i][0] = t0.x; q[i][1] = t0.y; q[i][2] = t0.z; q[i][3] = t0.w;
        q[i][4] = t1.x; q[i][5] = t1.y; q[i][6] = t1.z; q[i][7] = t1.w;
        q[i][8] = t2.x; q[i][9] = t2.y; q[i][10] = t2.z; q[i][11] = t2.w;
        q[i][12] = t3.x; q[i][13] = t3.y; q[i][14] = t3.z; q[i][15] = t3.w;
    }
    float O[4][16] = {};
    float Z[4] = {0.0f, 0.0f, 0.0f, 0.0f};
    const unsigned long long* bb = bits + (size_t)b * 128 * 32;
    const float* Kbase = Kt + ((size_t)b * 128 + h * 16) * NN;
    const float* Vbase = Vt + ((size_t)b * 128 + h * 16) * NN;
    for (int ch = 0; ch < 32; ++ch) {
        int n0 = ch * 64;
        __syncthreads();
        for (int e = tid; e < 1024; e += 256) {
            int d = e >> 6, i2 = e & 63;
            int n = n0 + i2;
            float kv = 0.0f, vv = 0.0f;
            if (n < NN) {
                kv = Kbase[(size_t)d * NN + n];
                vv = Vbase[(size_t)d * NN + n];
            }
            KT[d * 64 + i2] = kv;
            VT[d * 64 + i2] = vv;
        }
        unsigned long long w[4];
#pragma unroll
        for (int i = 0; i < 4; ++i) w[i] = bb[(gq * 4 + i) * 32 + ch];
        __syncthreads();
        float s[4][8] = {};
        const float4* K4 = (const float4*)KT;
#pragma unroll
        for (int d = 0; d < 16; ++d) {
            float4 ka = K4[d * 16 + nq], kb = K4[d * 16 + 8 + nq];
#pragma unroll
            for (int i = 0; i < 4; ++i) {
                float qv = q[i][d];
                s[i][0] += qv * ka.x; s[i][1] += qv * ka.y;
                s[i][2] += qv * ka.z; s[i][3] += qv * ka.w;
                s[i][4] += qv * kb.x; s[i][5] += qv * kb.y;
                s[i][6] += qv * kb.z; s[i][7] += qv * kb.w;
            }
        }
#pragma unroll
        for (int i = 0; i < 4; ++i) {
#pragma unroll
            for (int j = 0; j < 8; ++j) {
                int l = (j < 4) ? (4 * nq + j) : (32 + 4 * nq + (j - 4));
                float e = ((w[i] >> l) & 1ull) ? __expf(s[i][j]) : 0.0f;
                s[i][j] = e;
                Z[i] += e;
            }
        }
        const float4* V4 = (const float4*)VT;
#pragma unroll
        for (int d = 0; d < 16; ++d) {
            float4 va = V4[d * 16 + nq], vb = V4[d * 16 + 8 + nq];
#pragma unroll
            for (int i = 0; i < 4; ++i) {
                O[i][d] += s[i][0] * va.x + s[i][1] * va.y + s[i][2] * va.z + s[i][3] * va.w +
                           s[i][4] * vb.x + s[i][5] * vb.y + s[i][6] * vb.z + s[i][7] * vb.w;
            }
        }
    }
#pragma unroll
    for (int i = 0; i < 4; ++i) {
#pragma unroll
        for (int m = 1; m <= 4; m <<= 1) Z[i] += __shfl_xor(Z[i], m);
#pragma unroll
        for (int d = 0; d < 16; ++d) {
#pragma unroll
            for (int m = 1; m <= 4; m <<= 1) O[i][d] += __shfl_xor(O[i][d], m);
        }
    }
    if (nq == 0) {
#pragma unroll
        for (int i = 0; i < 4; ++i) {
            float inv = 1.0f / Z[i];
            int g = gq * 4 + i;
#pragma unroll
            for (int d = 0; d < 16; ++d) {
                MHt[((size_t)b * 128 + h * 16 + d) * 128 + g] = O[i][d] * inv;
            }
        }
    }
}

// ---- K8: FQt[b][c][g] = (MH[b][g]@WcT + bc)*rsqrt(H) ----
__global__ __launch_bounds__(256) void k_fq(const float* MHt, const float* WT, const float* bcv, float* FQt) {
    int b = blockIdx.x;
    int tid = threadIdx.x, xq = tid & 15, yq = tid >> 4;
    __shared__ float Bl[128 * 132];
    for (int e = tid; e < 16384; e += 256) {
        int j = e >> 7, g = e & 127;
        Bl[j * 132 + g] = MHt[(size_t)b * 16384 + e];
    }
    __syncthreads();
    const float* Wc = WT + 6 * 16384;
    float acc[8][8] = {};  // y = c, x = g
#pragma unroll 4
    for (int j = 0; j < 128; ++j) {
        const float4* Ar = (const float4*)(Wc + j * 128);
        float4 a0 = Ar[yq], a1 = Ar[16 + yq];
        const float4* Br = (const float4*)(Bl + j * 132);
        float4 b0 = Br[xq], b1 = Br[16 + xq];
        fma8x8(a0, a1, b0, b1, acc);
    }
    float4 bc0 = *(const float4*)(bcv + 4 * yq);
    float4 bc1 = *(const float4*)(bcv + 64 + 4 * yq);
    const float bcv8[8] = {bc0.x, bc0.y, bc0.z, bc0.w, bc1.x, bc1.y, bc1.z, bc1.w};
    const float sc = 0.08838834764831845f;  // 1/sqrt(128)
#pragma unroll
    for (int i = 0; i < 8; ++i) {
        int c = (i < 4) ? (4 * yq + i) : (64 + 4 * yq + (i - 4));
        float bci = bcv8[i];
        float* orow = FQt + ((size_t)b * 128 + c) * 128;
        *(float4*)(orow + 4 * xq) =
            make_float4((acc[i][0] + bci) * sc, (acc[i][1] + bci) * sc,
                        (acc[i][2] + bci) * sc, (acc[i][3] + bci) * sc);
        *(float4*)(orow + 64 + 4 * xq) =
            make_float4((acc[i][4] + bci) * sc, (acc[i][5] + bci) * sc,
                        (acc[i][6] + bci) * sc, (acc[i][7] + bci) * sc);
    }
}

// ---- K9: logits GEMM + tanh clip + masked exp; writes unnormalized p + row partial sums ----
__global__ __launch_bounds__(256) void k_logits(const float* emb, const float* FQt, const unsigned long long* bits,
                         float* out, float* Zp) {
    int nt = blockIdx.x, b = blockIdx.y;
    int tid = threadIdx.x, xq = tid & 15, yq = tid >> 4;
    int n0 = nt * 128;
    __shared__ float Al[64 * 132];
    __shared__ float Bl[64 * 132];
    float acc[8][8] = {};  // y = g, x = n
    for (int chh = 0; chh < 2; ++chh) {
        __syncthreads();
        for (int e = tid; e < 8192; e += 256) {
            int jl = e >> 7, g = e & 127;
            Al[jl * 132 + g] = FQt[((size_t)b * 128 + chh * 64 + jl) * 128 + g];
        }
        for (int e = tid; e < 8192; e += 256) {
            int jl = e & 63, r = e >> 6;
            int n = n0 + r;
            Bl[jl * 132 + r] = (n < NN) ? emb[((size_t)b * NN + n) * HH + chh * 64 + jl] : 0.0f;
        }
        __syncthreads();
#pragma unroll 4
        for (int jl = 0; jl < 64; ++jl) {
            const float4* Ar = (const float4*)(Al + jl * 132);
            float4 a0 = Ar[yq], a1 = Ar[16 + yq];
            const float4* Br = (const float4*)(Bl + jl * 132);
            float4 b0 = Br[xq], b1 = Br[16 + xq];
            fma8x8(a0, a1, b0, b1, acc);
        }
    }
    float psum[8];
    const unsigned long long* bb = bits + (size_t)b * 128 * 32;
#pragma unroll
    for (int i = 0; i < 8; ++i) {
        int g = (i < 4) ? (4 * yq + i) : (64 + 4 * yq + (i - 4));
        unsigned long long w0 = bb[g * 32 + nt * 2];
        unsigned long long w1 = bb[g * 32 + nt * 2 + 1];
        float* orow = out + ((size_t)b * 128 + g) * NN + n0;
        float ps = 0.0f;
        float pv[8];
#pragma unroll
        for (int k = 0; k < 8; ++k) {
            int nl = (k < 4) ? (4 * xq + k) : (64 + 4 * xq + (k - 4));
            unsigned long long w = (nl < 64) ? w0 : w1;
            int sh = nl & 63;
            float l = acc[i][k];
            float e2 = __expf(2.0f * l);
            float th = 1.0f - 2.0f / (e2 + 1.0f);
            float p = ((w >> sh) & 1ull) ? __expf(10.0f * th) : 0.0f;
            pv[k] = p;
            ps += p;
        }
        if (n0 + 4 * xq + 3 < NN)
            *(float4*)(orow + 4 * xq) = make_float4(pv[0], pv[1], pv[2], pv[3]);
        if (n0 + 64 + 4 * xq + 3 < NN)
            *(float4*)(orow + 64 + 4 * xq) = make_float4(pv[4], pv[5], pv[6], pv[7]);
        psum[i] = ps;
    }
#pragma unroll
    for (int i = 0; i < 8; ++i) {
#pragma unroll
        for (int m = 1; m <= 8; m <<= 1) psum[i] += __shfl_xor(psum[i], m);
    }
    if (xq == 0) {
#pragma unroll
        for (int i = 0; i < 8; ++i) {
            int g = (i < 4) ? (4 * yq + i) : (64 + 4 * yq + (i - 4));
            Zp[nt * 8192 + b * 128 + g] = psum[i];
        }
    }
}

// ---- K10: normalize probs ----
__global__ __launch_bounds__(256) void k_norm(const float* Zp, float* out) {
    int bg = blockIdx.x;
    __shared__ float invs;
    if (threadIdx.x == 0) {
        float s = 0.0f;
#pragma unroll
        for (int t = 0; t < 16; ++t) s += Zp[t * 8192 + bg];
        invs = 1.0f / s;
    }
    __syncthreads();
    float inv = invs;
    for (int n = threadIdx.x; n < NN; n += 256) out[(size_t)bg * NN + n] *= inv;
}

extern "C" void kernel_launch(void* const* d_in, const int* in_sizes, int n_in,
                              void* d_out, int out_size, void* d_ws, size_t ws_size,
                              hipStream_t stream) {
    const float* emb = (const float*)d_in[0];
    const float* mask = (const float*)d_in[1];
    const float* Wqg = (const float*)d_in[2];
    const float* Wqs = (const float*)d_in[3];
    const float* Wqt = (const float*)d_in[4];
    const float* Wql = (const float*)d_in[5];
    const float* Wk = (const float*)d_in[6];
    const float* Wv = (const float*)d_in[7];
    const float* Wc = (const float*)d_in[8];
    const float* bc = (const float*)d_in[9];
    const int* srcn = (const int*)d_in[10];
    const int* tgtn = (const int*)d_in[11];
    const int* lastn = (const int*)d_in[12];
    float* out = (float*)d_out;

    float* ws = (float*)d_ws;
    float* WT = ws;                         // 7*16384 = 114688
    float* gpart = ws + 114688;             // 131072
    float* qbase = ws + 245760;             // 8192
    float* Q = ws + 253952;                 // 1048576
    float* MHt = ws + 1302528;              // 1048576
    float* FQt = ws + 2351104;              // 1048576
    float* Zp = ws + 3399680;               // 131072
    float* Kt = ws + 3530752;               // 16384000
    float* Vt = ws + 19914752;              // 16384000
    unsigned long long* bits = (unsigned long long*)((char*)d_ws + (size_t)36298752 * 4);

    k_wt<<<7, 256, 0, stream>>>(Wqg, Wqs, Wqt, Wql, Wk, Wv, Wc, WT);
    k_maskbits<<<8192, 256, 0, stream>>>(mask, bits);
    k_gsum<<<dim3(16, 64), 128, 0, stream>>>(emb, gpart);
    k_kv<<<dim3(16, 64), 256, 0, stream>>>(emb, WT, Kt, Vt);
    k_qbase<<<64, 128, 0, stream>>>(emb, srcn, tgtn, gpart, WT, qbase);
    k_qlast<<<64, 256, 0, stream>>>(emb, lastn, WT, qbase, Q);
    k_flash<<<512, 256, 0, stream>>>(Kt, Vt, Q, bits, MHt);
    k_fq<<<64, 256, 0, stream>>>(MHt, WT, bc, FQt);
    k_logits<<<dim3(16, 64), 256, 0, stream>>>(emb, FQt, bits, out, Zp);
    k_norm<<<8192, 256, 0, stream>>>(Zp, out);
}

// Round 3
// 630.764 us; speedup vs baseline: 2.4037x; 1.0706x over previous
//
#include <hip/hip_runtime.h>
#include <hip/hip_bf16.h>

// Problem constants
#define BB 64
#define NN 2000
#define GG 128
#define HH 128
#define NHEAD 8
#define HD 16

__device__ __forceinline__ void fma8x8(const float4& a0, const float4& a1,
                                       const float4& b0, const float4& b1,
                                       float acc[8][8]) {
    const float av[8] = {a0.x, a0.y, a0.z, a0.w, a1.x, a1.y, a1.z, a1.w};
    const float bv[8] = {b0.x, b0.y, b0.z, b0.w, b1.x, b1.y, b1.z, b1.w};
#pragma unroll
    for (int i = 0; i < 8; ++i)
#pragma unroll
        for (int k = 0; k < 8; ++k) acc[i][k] += av[i] * bv[k];
}

// ---- K1: transpose 7 weight matrices (128x128): WT[m][j][c] = W_m[c][j] ----
__global__ __launch_bounds__(256) void k_wt(const float* w0, const float* w1, const float* w2,
                     const float* w3, const float* w4, const float* w5,
                     const float* w6, float* WT) {
    __shared__ float t[128 * 129];
    int m = blockIdx.x;
    const float* src = (m == 0) ? w0 : (m == 1) ? w1 : (m == 2) ? w2 :
                       (m == 3) ? w3 : (m == 4) ? w4 : (m == 5) ? w5 : w6;
    for (int e = threadIdx.x; e < 16384; e += 256) {
        int c = e >> 7, j = e & 127;
        t[c * 129 + j] = src[e];
    }
    __syncthreads();
    for (int e = threadIdx.x; e < 16384; e += 256) {
        int j = e >> 7, c = e & 127;
        WT[m * 16384 + e] = t[c * 129 + j];
    }
}

// ---- K2: mask -> bitmask. bits[(b*G+g)*32 + w] bit l = keep(n = w*64+l) ----
__global__ __launch_bounds__(256) void k_maskbits(const float* mask, unsigned long long* bits) {
    int bg = blockIdx.x;
    int lane = threadIdx.x & 63;
    int wv = threadIdx.x >> 6;
    for (int w = wv; w < 32; w += 4) {
        int n = w * 64 + lane;
        bool keep = false;
        if (n < NN) keep = (mask[(size_t)bg * NN + n] == 0.0f);
        unsigned long long bal = __ballot(keep);
        if (lane == 0) bits[bg * 32 + w] = bal;
    }
}

// ---- K3: partial column sums of embeddings (for graph mean) ----
__global__ __launch_bounds__(128) void k_gsum(const float* emb, float* gpart) {
    int ck = blockIdx.x, b = blockIdx.y, c = threadIdx.x;
    const float* p = emb + ((size_t)b * NN + ck * 125) * HH + c;
    float s = 0.0f;
#pragma unroll 5
    for (int r = 0; r < 125; ++r) s += p[(size_t)r * HH];
    gpart[ck * 8192 + b * 128 + c] = s;
}

// ---- K4: qbase[b][c] = graph@WqgT + src@WqsT + tgt@WqtT ----
__global__ __launch_bounds__(128) void k_qbase(const float* emb, const int* srcn, const int* tgtn,
                        const float* gpart, const float* WT, float* qbase) {
    int b = blockIdx.x, c = threadIdx.x;
    __shared__ float ge[128], se[128], te[128];
    float s = 0.0f;
#pragma unroll
    for (int t = 0; t < 16; ++t) s += gpart[t * 8192 + b * 128 + c];
    ge[c] = s * (1.0f / 2000.0f);
    se[c] = emb[((size_t)b * NN + srcn[b]) * HH + c];
    te[c] = emb[((size_t)b * NN + tgtn[b]) * HH + c];
    __syncthreads();
    const float* Wg = WT;
    const float* Ws = WT + 16384;
    const float* Wt2 = WT + 32768;
    float acc = 0.0f;
#pragma unroll 4
    for (int j = 0; j < 128; ++j) {
        acc += ge[j] * Wg[j * 128 + c] + se[j] * Ws[j * 128 + c] + te[j] * Wt2[j * 128 + c];
    }
    qbase[b * 128 + c] = acc;
}

// ---- K5: Q[b][g][c] = 0.25*(qbase[b][c] + lastemb[b][g]@WqlT) ----
__global__ __launch_bounds__(256) void k_qlast(const float* emb, const int* lastn, const float* WT,
                        const float* qbase, float* Q) {
    int b = blockIdx.x;
    int tid = threadIdx.x, xq = tid & 15, yq = tid >> 4;
    __shared__ float Bl[128 * 132];
    for (int e = tid; e < 16384; e += 256) {
        int g = e >> 7, j = e & 127;
        Bl[j * 132 + g] = emb[((size_t)b * NN + lastn[b * 128 + g]) * HH + j];
    }
    __syncthreads();
    const float* Wql = WT + 3 * 16384;
    float acc[8][8] = {};  // y = c (from Wql), x = g (from Bl)
#pragma unroll 4
    for (int j = 0; j < 128; ++j) {
        const float4* Ar = (const float4*)(Wql + j * 128);
        float4 a0 = Ar[yq], a1 = Ar[16 + yq];
        const float4* Br = (const float4*)(Bl + j * 132);
        float4 b0 = Br[xq], b1 = Br[16 + xq];
        fma8x8(a0, a1, b0, b1, acc);
    }
    float4 qb0 = *(const float4*)(qbase + b * 128 + 4 * yq);
    float4 qb1 = *(const float4*)(qbase + b * 128 + 64 + 4 * yq);
#pragma unroll
    for (int k = 0; k < 8; ++k) {
        int g = (k < 4) ? (4 * xq + k) : (64 + 4 * xq + (k - 4));
        float* orow = Q + ((size_t)b * 128 + g) * 128;
        float4 v0 = make_float4((acc[0][k] + qb0.x) * 0.25f, (acc[1][k] + qb0.y) * 0.25f,
                                (acc[2][k] + qb0.z) * 0.25f, (acc[3][k] + qb0.w) * 0.25f);
        float4 v1 = make_float4((acc[4][k] + qb1.x) * 0.25f, (acc[5][k] + qb1.y) * 0.25f,
                                (acc[6][k] + qb1.z) * 0.25f, (acc[7][k] + qb1.w) * 0.25f);
        *(float4*)(orow + 4 * yq) = v0;
        *(float4*)(orow + 64 + 4 * yq) = v1;
    }
}

// ---- K6: K/V projections -> Kt[b][c][n], Vt[b][c][n] ----
__global__ __launch_bounds__(256) void k_kv(const float* emb, const float* WT, float* Kt, float* Vt) {
    int nt = blockIdx.x, b = blockIdx.y;
    int tid = threadIdx.x, xq = tid & 15, yq = tid >> 4;
    int n0 = nt * 128;
    __shared__ float Al[64 * 132];
    __shared__ float Bl[64 * 132];
    for (int gemm = 0; gemm < 2; ++gemm) {
        const float* Wsrc = WT + (4 + gemm) * 16384;
        float* out = gemm ? Vt : Kt;
        float acc[8][8] = {};
        for (int jh = 0; jh < 2; ++jh) {
            __syncthreads();
            for (int e = tid; e < 8192; e += 256) {
                int jl = e >> 7, c = e & 127;
                Al[jl * 132 + c] = Wsrc[(jh * 64 + jl) * 128 + c];
            }
            for (int e = tid; e < 8192; e += 256) {
                int jl = e & 63, r = e >> 6;
                int n = n0 + r;
                Bl[jl * 132 + r] = (n < NN) ? emb[((size_t)b * NN + n) * HH + jh * 64 + jl] : 0.0f;
            }
            __syncthreads();
#pragma unroll 4
            for (int jl = 0; jl < 64; ++jl) {
                const float4* Ar = (const float4*)(Al + jl * 132);
                float4 a0 = Ar[yq], a1 = Ar[16 + yq];
                const float4* Br = (const float4*)(Bl + jl * 132);
                float4 b0 = Br[xq], b1 = Br[16 + xq];
                fma8x8(a0, a1, b0, b1, acc);
            }
        }
#pragma unroll
        for (int i = 0; i < 8; ++i) {
            int c = (i < 4) ? (4 * yq + i) : (64 + 4 * yq + (i - 4));
            float* orow = out + ((size_t)b * 128 + c) * NN + n0;
            int nA = 4 * xq;
            if (n0 + nA + 3 < NN)
                *(float4*)(orow + nA) = make_float4(acc[i][0], acc[i][1], acc[i][2], acc[i][3]);
            int nB = 64 + 4 * xq;
            if (n0 + nB + 3 < NN)
                *(float4*)(orow + nB) = make_float4(acc[i][4], acc[i][5], acc[i][6], acc[i][7]);
        }
    }
}

// ---- K7: flash attention, 4-way n-split per (b,h); partial O/Z out ----
// grid 2048: bid = ((b*8 + h)*4 + s4); each block does chunks [s4*8, s4*8+8)
__global__ __launch_bounds__(256) void k_flash(const float* Kt, const float* Vt, const float* Q,
                        const unsigned long long* bits, float* Opart, float* Zpart) {
    int bid = blockIdx.x;
    int s4 = bid & 3, h = (bid >> 2) & 7, b = bid >> 5;
    int tid = threadIdx.x, gq = tid >> 3, nq = tid & 7;
    __shared__ float KT[16 * 64];
    __shared__ float VT[16 * 64];
    float q[4][16];
#pragma unroll
    for (int i = 0; i < 4; ++i) {
        const float4* Qr = (const float4*)(Q + ((size_t)b * 128 + gq * 4 + i) * 128 + h * 16);
        float4 t0 = Qr[0], t1 = Qr[1], t2 = Qr[2], t3 = Qr[3];
        q[i][0] = t0.x; q[i][1] = t0.y; q[i][2] = t0.z; q[i][3] = t0.w;
        q[i][4] = t1.x; q[i][5] = t1.y; q[i][6] = t1.z; q[i][7] = t1.w;
        q[i][8] = t2.x; q[i][9] = t2.y; q[i][10] = t2.z; q[i][11] = t2.w;
        q[i][12] = t3.x; q[i][13] = t3.y; q[i][14] = t3.z; q[i][15] = t3.w;
    }
    float O[4][16] = {};
    float Z[4] = {0.0f, 0.0f, 0.0f, 0.0f};
    const unsigned long long* bb = bits + (size_t)b * 128 * 32;
    const float* Kbase = Kt + ((size_t)b * 128 + h * 16) * NN;
    const float* Vbase = Vt + ((size_t)b * 128 + h * 16) * NN;
    int sd = tid >> 4, si = tid & 15;  // staging: row sd in [0,16), float4 si in [0,16)
    int ch0 = s4 * 8;
    for (int ch = ch0; ch < ch0 + 8; ++ch) {
        int n0 = ch * 64;
        __syncthreads();
        {
            int n = n0 + si * 4;
            float4 kv = make_float4(0.f, 0.f, 0.f, 0.f);
            float4 vv = make_float4(0.f, 0.f, 0.f, 0.f);
            if (n + 3 < NN) {
                kv = *(const float4*)(Kbase + (size_t)sd * NN + n);
                vv = *(const float4*)(Vbase + (size_t)sd * NN + n);
            }
            *(float4*)(KT + sd * 64 + si * 4) = kv;
            *(float4*)(VT + sd * 64 + si * 4) = vv;
        }
        unsigned long long w[4];
#pragma unroll
        for (int i = 0; i < 4; ++i) w[i] = bb[(gq * 4 + i) * 32 + ch];
        __syncthreads();
        float s[4][8] = {};
        const float4* K4 = (const float4*)KT;
#pragma unroll
        for (int d = 0; d < 16; ++d) {
            float4 ka = K4[d * 16 + nq], kb = K4[d * 16 + 8 + nq];
#pragma unroll
            for (int i = 0; i < 4; ++i) {
                float qv = q[i][d];
                s[i][0] += qv * ka.x; s[i][1] += qv * ka.y;
                s[i][2] += qv * ka.z; s[i][3] += qv * ka.w;
                s[i][4] += qv * kb.x; s[i][5] += qv * kb.y;
                s[i][6] += qv * kb.z; s[i][7] += qv * kb.w;
            }
        }
#pragma unroll
        for (int i = 0; i < 4; ++i) {
#pragma unroll
            for (int j = 0; j < 8; ++j) {
                int l = (j < 4) ? (4 * nq + j) : (32 + 4 * nq + (j - 4));
                float e = ((w[i] >> l) & 1ull) ? __expf(s[i][j]) : 0.0f;
                s[i][j] = e;
                Z[i] += e;
            }
        }
        const float4* V4 = (const float4*)VT;
#pragma unroll
        for (int d = 0; d < 16; ++d) {
            float4 va = V4[d * 16 + nq], vb = V4[d * 16 + 8 + nq];
#pragma unroll
            for (int i = 0; i < 4; ++i) {
                O[i][d] += s[i][0] * va.x + s[i][1] * va.y + s[i][2] * va.z + s[i][3] * va.w +
                           s[i][4] * vb.x + s[i][5] * vb.y + s[i][6] * vb.z + s[i][7] * vb.w;
            }
        }
    }
#pragma unroll
    for (int i = 0; i < 4; ++i) {
#pragma unroll
        for (int m = 1; m <= 4; m <<= 1) Z[i] += __shfl_xor(Z[i], m);
#pragma unroll
        for (int d = 0; d < 16; ++d) {
#pragma unroll
            for (int m = 1; m <= 4; m <<= 1) O[i][d] += __shfl_xor(O[i][d], m);
        }
    }
    if (nq == 0) {
#pragma unroll
        for (int i = 0; i < 4; ++i) {
            int g = gq * 4 + i;
            Zpart[(((size_t)s4 * 64 + b) * 8 + h) * 128 + g] = Z[i];
#pragma unroll
            for (int d = 0; d < 16; ++d) {
                Opart[((((size_t)s4 * 64 + b) * 8 + h) * 16 + d) * 128 + g] = O[i][d];
            }
        }
    }
}

// ---- K7b: combine partials -> MHt[b][h*16+d][g] ----
__global__ __launch_bounds__(256) void k_ocomb(const float* Opart, const float* Zpart, float* MHt) {
    int bh = blockIdx.x;  // 512
    int b = bh >> 3, h = bh & 7;
    int tid = threadIdx.x;
    for (int e = tid; e < 2048; e += 256) {
        int d = e >> 7, g = e & 127;
        float z = 0.0f, o = 0.0f;
#pragma unroll
        for (int s = 0; s < 4; ++s) {
            z += Zpart[(((size_t)s * 64 + b) * 8 + h) * 128 + g];
            o += Opart[((((size_t)s * 64 + b) * 8 + h) * 16 + d) * 128 + g];
        }
        MHt[((size_t)b * 128 + h * 16 + d) * 128 + g] = o / z;
    }
}

// ---- K8: FQt[b][c][g] = (MH[b][g]@WcT + bc)*rsqrt(H) ----
__global__ __launch_bounds__(256) void k_fq(const float* MHt, const float* WT, const float* bcv, float* FQt) {
    int b = blockIdx.x;
    int tid = threadIdx.x, xq = tid & 15, yq = tid >> 4;
    __shared__ float Bl[128 * 132];
    for (int e = tid; e < 16384; e += 256) {
        int j = e >> 7, g = e & 127;
        Bl[j * 132 + g] = MHt[(size_t)b * 16384 + e];
    }
    __syncthreads();
    const float* Wc = WT + 6 * 16384;
    float acc[8][8] = {};  // y = c, x = g
#pragma unroll 4
    for (int j = 0; j < 128; ++j) {
        const float4* Ar = (const float4*)(Wc + j * 128);
        float4 a0 = Ar[yq], a1 = Ar[16 + yq];
        const float4* Br = (const float4*)(Bl + j * 132);
        float4 b0 = Br[xq], b1 = Br[16 + xq];
        fma8x8(a0, a1, b0, b1, acc);
    }
    float4 bc0 = *(const float4*)(bcv + 4 * yq);
    float4 bc1 = *(const float4*)(bcv + 64 + 4 * yq);
    const float bcv8[8] = {bc0.x, bc0.y, bc0.z, bc0.w, bc1.x, bc1.y, bc1.z, bc1.w};
    const float sc = 0.08838834764831845f;  // 1/sqrt(128)
#pragma unroll
    for (int i = 0; i < 8; ++i) {
        int c = (i < 4) ? (4 * yq + i) : (64 + 4 * yq + (i - 4));
        float bci = bcv8[i];
        float* orow = FQt + ((size_t)b * 128 + c) * 128;
        *(float4*)(orow + 4 * xq) =
            make_float4((acc[i][0] + bci) * sc, (acc[i][1] + bci) * sc,
                        (acc[i][2] + bci) * sc, (acc[i][3] + bci) * sc);
        *(float4*)(orow + 64 + 4 * xq) =
            make_float4((acc[i][4] + bci) * sc, (acc[i][5] + bci) * sc,
                        (acc[i][6] + bci) * sc, (acc[i][7] + bci) * sc);
    }
}

// ---- K9: logits GEMM + tanh clip + masked exp; writes unnormalized p + row partial sums ----
__global__ __launch_bounds__(256) void k_logits(const float* emb, const float* FQt, const unsigned long long* bits,
                         float* out, float* Zp) {
    int nt = blockIdx.x, b = blockIdx.y;
    int tid = threadIdx.x, xq = tid & 15, yq = tid >> 4;
    int n0 = nt * 128;
    __shared__ float Al[64 * 132];
    __shared__ float Bl[64 * 132];
    float acc[8][8] = {};  // y = g, x = n
    for (int chh = 0; chh < 2; ++chh) {
        __syncthreads();
        for (int e = tid; e < 8192; e += 256) {
            int jl = e >> 7, g = e & 127;
            Al[jl * 132 + g] = FQt[((size_t)b * 128 + chh * 64 + jl) * 128 + g];
        }
        for (int e = tid; e < 8192; e += 256) {
            int jl = e & 63, r = e >> 6;
            int n = n0 + r;
            Bl[jl * 132 + r] = (n < NN) ? emb[((size_t)b * NN + n) * HH + chh * 64 + jl] : 0.0f;
        }
        __syncthreads();
#pragma unroll 4
        for (int jl = 0; jl < 64; ++jl) {
            const float4* Ar = (const float4*)(Al + jl * 132);
            float4 a0 = Ar[yq], a1 = Ar[16 + yq];
            const float4* Br = (const float4*)(Bl + jl * 132);
            float4 b0 = Br[xq], b1 = Br[16 + xq];
            fma8x8(a0, a1, b0, b1, acc);
        }
    }
    float psum[8];
    const unsigned long long* bb = bits + (size_t)b * 128 * 32;
#pragma unroll
    for (int i = 0; i < 8; ++i) {
        int g = (i < 4) ? (4 * yq + i) : (64 + 4 * yq + (i - 4));
        unsigned long long w0 = bb[g * 32 + nt * 2];
        unsigned long long w1 = bb[g * 32 + nt * 2 + 1];
        float* orow = out + ((size_t)b * 128 + g) * NN + n0;
        float ps = 0.0f;
        float pv[8];
#pragma unroll
        for (int k = 0; k < 8; ++k) {
            int nl = (k < 4) ? (4 * xq + k) : (64 + 4 * xq + (k - 4));
            unsigned long long w = (nl < 64) ? w0 : w1;
            int sh = nl & 63;
            float l = acc[i][k];
            float e2 = __expf(2.0f * l);
            float th = 1.0f - 2.0f / (e2 + 1.0f);
            float p = ((w >> sh) & 1ull) ? __expf(10.0f * th) : 0.0f;
            pv[k] = p;
            ps += p;
        }
        if (n0 + 4 * xq + 3 < NN)
            *(float4*)(orow + 4 * xq) = make_float4(pv[0], pv[1], pv[2], pv[3]);
        if (n0 + 64 + 4 * xq + 3 < NN)
            *(float4*)(orow + 64 + 4 * xq) = make_float4(pv[4], pv[5], pv[6], pv[7]);
        psum[i] = ps;
    }
#pragma unroll
    for (int i = 0; i < 8; ++i) {
#pragma unroll
        for (int m = 1; m <= 8; m <<= 1) psum[i] += __shfl_xor(psum[i], m);
    }
    if (xq == 0) {
#pragma unroll
        for (int i = 0; i < 8; ++i) {
            int g = (i < 4) ? (4 * yq + i) : (64 + 4 * yq + (i - 4));
            Zp[nt * 8192 + b * 128 + g] = psum[i];
        }
    }
}

// ---- K10: normalize probs ----
__global__ __launch_bounds__(256) void k_norm(const float* Zp, float* out) {
    int bg = blockIdx.x;
    __shared__ float invs;
    if (threadIdx.x == 0) {
        float s = 0.0f;
#pragma unroll
        for (int t = 0; t < 16; ++t) s += Zp[t * 8192 + bg];
        invs = 1.0f / s;
    }
    __syncthreads();
    float inv = invs;
    for (int n = threadIdx.x; n < NN; n += 256) out[(size_t)bg * NN + n] *= inv;
}

extern "C" void kernel_launch(void* const* d_in, const int* in_sizes, int n_in,
                              void* d_out, int out_size, void* d_ws, size_t ws_size,
                              hipStream_t stream) {
    const float* emb = (const float*)d_in[0];
    const float* mask = (const float*)d_in[1];
    const float* Wqg = (const float*)d_in[2];
    const float* Wqs = (const float*)d_in[3];
    const float* Wqt = (const float*)d_in[4];
    const float* Wql = (const float*)d_in[5];
    const float* Wk = (const float*)d_in[6];
    const float* Wv = (const float*)d_in[7];
    const float* Wc = (const float*)d_in[8];
    const float* bc = (const float*)d_in[9];
    const int* srcn = (const int*)d_in[10];
    const int* tgtn = (const int*)d_in[11];
    const int* lastn = (const int*)d_in[12];
    float* out = (float*)d_out;

    float* ws = (float*)d_ws;
    float* WT = ws;                         // 7*16384 = 114688
    float* gpart = ws + 114688;             // 131072
    float* qbase = ws + 245760;             // 8192
    float* Q = ws + 253952;                 // 1048576
    float* MHt = ws + 1302528;              // 1048576
    float* FQt = ws + 2351104;              // 1048576
    float* Zp = ws + 3399680;               // 131072
    float* Kt = ws + 3530752;               // 16384000
    float* Vt = ws + 19914752;              // 16384000
    unsigned long long* bits = (unsigned long long*)((char*)d_ws + (size_t)36298752 * 4);

    // flash partials live in d_out (overwritten later by k_logits):
    // Opart: 4*64*8*16*128 = 4194304 floats; Zpart: 4*64*8*128 = 262144 floats
    float* Opart = out;
    float* Zpart = out + 4194304;

    k_wt<<<7, 256, 0, stream>>>(Wqg, Wqs, Wqt, Wql, Wk, Wv, Wc, WT);
    k_maskbits<<<8192, 256, 0, stream>>>(mask, bits);
    k_gsum<<<dim3(16, 64), 128, 0, stream>>>(emb, gpart);
    k_kv<<<dim3(16, 64), 256, 0, stream>>>(emb, WT, Kt, Vt);
    k_qbase<<<64, 128, 0, stream>>>(emb, srcn, tgtn, gpart, WT, qbase);
    k_qlast<<<64, 256, 0, stream>>>(emb, lastn, WT, qbase, Q);
    k_flash<<<2048, 256, 0, stream>>>(Kt, Vt, Q, bits, Opart, Zpart);
    k_ocomb<<<512, 256, 0, stream>>>(Opart, Zpart, MHt);
    k_fq<<<64, 256, 0, stream>>>(MHt, WT, bc, FQt);
    k_logits<<<dim3(16, 64), 256, 0, stream>>>(emb, FQt, bits, out, Zp);
    k_norm<<<8192, 256, 0, stream>>>(Zp, out);
}

// Round 4
// 489.094 us; speedup vs baseline: 3.0999x; 1.2897x over previous
//
#include <hip/hip_runtime.h>
#include <hip/hip_bf16.h>

#define BB 64
#define NN 2000
#define GG 128
#define HH 128
#define NHEAD 8
#define HD 16

typedef __attribute__((ext_vector_type(8))) short short8;
typedef __attribute__((ext_vector_type(4))) float f32x4;

__device__ __forceinline__ unsigned short bf16hi(float f) {
    union { float f; unsigned u; } v; v.f = f;
    return (unsigned short)(v.u >> 16);
}
__device__ __forceinline__ float bf16tof(unsigned short h) {
    union { float f; unsigned u; } v; v.u = ((unsigned)h) << 16;
    return v.f;
}

__device__ __forceinline__ void fma8x8(const float4& a0, const float4& a1,
                                       const float4& b0, const float4& b1,
                                       float acc[8][8]) {
    const float av[8] = {a0.x, a0.y, a0.z, a0.w, a1.x, a1.y, a1.z, a1.w};
    const float bv[8] = {b0.x, b0.y, b0.z, b0.w, b1.x, b1.y, b1.z, b1.w};
#pragma unroll
    for (int i = 0; i < 8; ++i)
#pragma unroll
        for (int k = 0; k < 8; ++k) acc[i][k] += av[i] * bv[k];
}

// ---- K1: transpose 7 weight matrices (128x128): WT[m][j][c] = W_m[c][j] ----
__global__ __launch_bounds__(256) void k_wt(const float* w0, const float* w1, const float* w2,
                     const float* w3, const float* w4, const float* w5,
                     const float* w6, float* WT) {
    __shared__ float t[128 * 129];
    int m = blockIdx.x;
    const float* src = (m == 0) ? w0 : (m == 1) ? w1 : (m == 2) ? w2 :
                       (m == 3) ? w3 : (m == 4) ? w4 : (m == 5) ? w5 : w6;
    for (int e = threadIdx.x; e < 16384; e += 256) {
        int c = e >> 7, j = e & 127;
        t[c * 129 + j] = src[e];
    }
    __syncthreads();
    for (int e = threadIdx.x; e < 16384; e += 256) {
        int j = e >> 7, c = e & 127;
        WT[m * 16384 + e] = t[c * 129 + j];
    }
}

// ---- K2: mask -> bitmask ----
__global__ __launch_bounds__(256) void k_maskbits(const float* mask, unsigned long long* bits) {
    int bg = blockIdx.x;
    int lane = threadIdx.x & 63;
    int wv = threadIdx.x >> 6;
    for (int w = wv; w < 32; w += 4) {
        int n = w * 64 + lane;
        bool keep = false;
        if (n < NN) keep = (mask[(size_t)bg * NN + n] == 0.0f);
        unsigned long long bal = __ballot(keep);
        if (lane == 0) bits[bg * 32 + w] = bal;
    }
}

// ---- K3: partial column sums of embeddings ----
__global__ __launch_bounds__(128) void k_gsum(const float* emb, float* gpart) {
    int ck = blockIdx.x, b = blockIdx.y, c = threadIdx.x;
    const float* p = emb + ((size_t)b * NN + ck * 125) * HH + c;
    float s = 0.0f;
#pragma unroll 5
    for (int r = 0; r < 125; ++r) s += p[(size_t)r * HH];
    gpart[ck * 8192 + b * 128 + c] = s;
}

// ---- K4: qbase ----
__global__ __launch_bounds__(128) void k_qbase(const float* emb, const int* srcn, const int* tgtn,
                        const float* gpart, const float* WT, float* qbase) {
    int b = blockIdx.x, c = threadIdx.x;
    __shared__ float ge[128], se[128], te[128];
    float s = 0.0f;
#pragma unroll
    for (int t = 0; t < 16; ++t) s += gpart[t * 8192 + b * 128 + c];
    ge[c] = s * (1.0f / 2000.0f);
    se[c] = emb[((size_t)b * NN + srcn[b]) * HH + c];
    te[c] = emb[((size_t)b * NN + tgtn[b]) * HH + c];
    __syncthreads();
    const float* Wg = WT;
    const float* Ws = WT + 16384;
    const float* Wt2 = WT + 32768;
    float acc = 0.0f;
#pragma unroll 4
    for (int j = 0; j < 128; ++j) {
        acc += ge[j] * Wg[j * 128 + c] + se[j] * Ws[j * 128 + c] + te[j] * Wt2[j * 128 + c];
    }
    qbase[b * 128 + c] = acc;
}

// ---- K5: Qhl[b][g][128] (bf16 hi/lo) = 0.25*(qbase + lastemb@WqlT) ----
__global__ __launch_bounds__(256) void k_qlast(const float* emb, const int* lastn, const float* WT,
                        const float* qbase, unsigned short* Qhi, unsigned short* Qlo) {
    int b = blockIdx.x;
    int tid = threadIdx.x, xq = tid & 15, yq = tid >> 4;
    __shared__ float Bl[128 * 132];
    for (int e = tid; e < 16384; e += 256) {
        int g = e >> 7, j = e & 127;
        Bl[j * 132 + g] = emb[((size_t)b * NN + lastn[b * 128 + g]) * HH + j];
    }
    __syncthreads();
    const float* Wql = WT + 3 * 16384;
    float acc[8][8] = {};
#pragma unroll 4
    for (int j = 0; j < 128; ++j) {
        const float4* Ar = (const float4*)(Wql + j * 128);
        float4 a0 = Ar[yq], a1 = Ar[16 + yq];
        const float4* Br = (const float4*)(Bl + j * 132);
        float4 b0 = Br[xq], b1 = Br[16 + xq];
        fma8x8(a0, a1, b0, b1, acc);
    }
    float4 qb0 = *(const float4*)(qbase + b * 128 + 4 * yq);
    float4 qb1 = *(const float4*)(qbase + b * 128 + 64 + 4 * yq);
    const float q0v[4] = {qb0.x, qb0.y, qb0.z, qb0.w};
    const float q1v[4] = {qb1.x, qb1.y, qb1.z, qb1.w};
#pragma unroll
    for (int k = 0; k < 8; ++k) {
        int g = (k < 4) ? (4 * xq + k) : (64 + 4 * xq + (k - 4));
        size_t base = ((size_t)b * 128 + g) * 128;
        unsigned short h4[4], l4[4];
#pragma unroll
        for (int i = 0; i < 4; ++i) {
            float f = (acc[i][k] + q0v[i]) * 0.25f;
            h4[i] = bf16hi(f); l4[i] = bf16hi(f - bf16tof(h4[i]));
        }
        uint2 ph, pl;
        ph.x = (unsigned)h4[0] | ((unsigned)h4[1] << 16); ph.y = (unsigned)h4[2] | ((unsigned)h4[3] << 16);
        pl.x = (unsigned)l4[0] | ((unsigned)l4[1] << 16); pl.y = (unsigned)l4[2] | ((unsigned)l4[3] << 16);
        *(uint2*)(Qhi + base + 4 * yq) = ph;
        *(uint2*)(Qlo + base + 4 * yq) = pl;
#pragma unroll
        for (int i = 0; i < 4; ++i) {
            float f = (acc[4 + i][k] + q1v[i]) * 0.25f;
            h4[i] = bf16hi(f); l4[i] = bf16hi(f - bf16tof(h4[i]));
        }
        ph.x = (unsigned)h4[0] | ((unsigned)h4[1] << 16); ph.y = (unsigned)h4[2] | ((unsigned)h4[3] << 16);
        pl.x = (unsigned)l4[0] | ((unsigned)l4[1] << 16); pl.y = (unsigned)l4[2] | ((unsigned)l4[3] << 16);
        *(uint2*)(Qhi + base + 64 + 4 * yq) = ph;
        *(uint2*)(Qlo + base + 64 + 4 * yq) = pl;
    }
}

// ---- K6: K/V projections -> Khl[b][h][n][16], Vhl[b][h][d][2000] (bf16 hi/lo) ----
__global__ __launch_bounds__(256) void k_kv(const float* emb, const float* WT,
                                            unsigned short* Khi, unsigned short* Klo,
                                            unsigned short* Vhi, unsigned short* Vlo) {
    int nt = blockIdx.x, b = blockIdx.y;
    int tid = threadIdx.x, xq = tid & 15, yq = tid >> 4;
    int n0 = nt * 128;
    __shared__ float Al[64 * 132];
    __shared__ float Bl[64 * 132];
    for (int gemm = 0; gemm < 2; ++gemm) {
        const float* Wsrc = WT + (4 + gemm) * 16384;
        float acc[8][8] = {};
        for (int jh = 0; jh < 2; ++jh) {
            __syncthreads();
            for (int e = tid; e < 8192; e += 256) {
                int jl = e >> 7, c = e & 127;
                Al[jl * 132 + c] = Wsrc[(jh * 64 + jl) * 128 + c];
            }
            for (int e = tid; e < 8192; e += 256) {
                int jl = e & 63, r = e >> 6;
                int n = n0 + r;
                Bl[jl * 132 + r] = (n < NN) ? emb[((size_t)b * NN + n) * HH + jh * 64 + jl] : 0.0f;
            }
            __syncthreads();
#pragma unroll 4
            for (int jl = 0; jl < 64; ++jl) {
                const float4* Ar = (const float4*)(Al + jl * 132);
                float4 a0 = Ar[yq], a1 = Ar[16 + yq];
                const float4* Br = (const float4*)(Bl + jl * 132);
                float4 b0 = Br[xq], b1 = Br[16 + xq];
                fma8x8(a0, a1, b0, b1, acc);
            }
        }
        if (gemm == 0) {
            // K: [b][h][n][16]; pack along d (i4)
#pragma unroll
            for (int ig = 0; ig < 2; ++ig) {
                int cb = ig * 64 + 4 * yq;
                int h = cb >> 4, d4 = cb & 15;
#pragma unroll
                for (int kk = 0; kk < 8; ++kk) {
                    int n = n0 + ((kk < 4) ? (4 * xq + kk) : (64 + 4 * xq + kk - 4));
                    if (n < NN) {
                        unsigned short h4[4], l4[4];
#pragma unroll
                        for (int i4 = 0; i4 < 4; ++i4) {
                            float f = acc[ig * 4 + i4][kk];
                            h4[i4] = bf16hi(f); l4[i4] = bf16hi(f - bf16tof(h4[i4]));
                        }
                        uint2 ph, pl;
                        ph.x = (unsigned)h4[0] | ((unsigned)h4[1] << 16); ph.y = (unsigned)h4[2] | ((unsigned)h4[3] << 16);
                        pl.x = (unsigned)l4[0] | ((unsigned)l4[1] << 16); pl.y = (unsigned)l4[2] | ((unsigned)l4[3] << 16);
                        size_t base = (((size_t)b * 8 + h) * 2000 + n) * 16 + d4;
                        *(uint2*)(Khi + base) = ph;
                        *(uint2*)(Klo + base) = pl;
                    }
                }
            }
        } else {
            // V: [b][h][d][2000]; pack along n (k within group)
#pragma unroll
            for (int i = 0; i < 8; ++i) {
                int c = (i < 4) ? (4 * yq + i) : (64 + 4 * yq + (i - 4));
                int h = c >> 4, d = c & 15;
#pragma unroll
                for (int kg = 0; kg < 2; ++kg) {
                    int nA = n0 + kg * 64 + 4 * xq;
                    if (nA + 3 < NN) {
                        unsigned short h4[4], l4[4];
#pragma unroll
                        for (int j = 0; j < 4; ++j) {
                            float f = acc[i][kg * 4 + j];
                            h4[j] = bf16hi(f); l4[j] = bf16hi(f - bf16tof(h4[j]));
                        }
                        uint2 ph, pl;
                        ph.x = (unsigned)h4[0] | ((unsigned)h4[1] << 16); ph.y = (unsigned)h4[2] | ((unsigned)h4[3] << 16);
                        pl.x = (unsigned)l4[0] | ((unsigned)l4[1] << 16); pl.y = (unsigned)l4[2] | ((unsigned)l4[3] << 16);
                        size_t base = (((size_t)b * 8 + h) * 16 + d) * 2000 + nA;
                        *(uint2*)(Vhi + base) = ph;
                        *(uint2*)(Vlo + base) = pl;
                    }
                }
            }
        }
    }
}

// ---- K7: MFMA flash attention (split-bf16), 4-way n-split per (b,h) ----
// S^T = K·Q^T  (A = K[n][d] chunk, B = Q^T);  O^T = V^T·P  (A = V^T[d][n], B = P[n][g])
__global__ __launch_bounds__(256) void k_flash(const unsigned short* Khi, const unsigned short* Klo,
                        const unsigned short* Vhi, const unsigned short* Vlo,
                        const unsigned short* Qhi, const unsigned short* Qlo,
                        const unsigned long long* bits, float* Opart, float* Zpart) {
    int bid = blockIdx.x;
    int s4 = bid & 3, h = (bid >> 2) & 7, b = bid >> 5;
    int tid = threadIdx.x;
    int wv = tid >> 6, lane = tid & 63, l15 = lane & 15, q3 = lane >> 4;

    __shared__ unsigned short Klds[2][64][24];   // [hi/lo][n][d(16)+pad8]
    __shared__ unsigned short Vlds[2][16][72];   // [hi/lo][d][n(64)+pad8]
    __shared__ unsigned short Plds[4][2][32][72];// [wave][hi/lo][g][n+pad8]

    const short8 z8 = {0, 0, 0, 0, 0, 0, 0, 0};

    // Q fragments (per-block constant): B-frag col=l15 -> g, k=8*q3+j -> d
    short8 qf[2][2];
#pragma unroll
    for (int gt = 0; gt < 2; ++gt) {
        int g = wv * 32 + gt * 16 + l15;
        if (q3 < 2) {
            size_t off = ((size_t)b * 128 + g) * 128 + h * 16 + q3 * 8;
            qf[gt][0] = *(const short8*)(Qhi + off);
            qf[gt][1] = *(const short8*)(Qlo + off);
        } else {
            qf[gt][0] = z8; qf[gt][1] = z8;
        }
    }

    f32x4 Oacc[2] = {{0.f, 0.f, 0.f, 0.f}, {0.f, 0.f, 0.f, 0.f}};
    float zacc[2] = {0.f, 0.f};

    const unsigned long long* bb0 = bits + (((size_t)b * 128 + wv * 32 + l15) * 32);
    const unsigned long long* bb1 = bb0 + 16 * 32;

    size_t kvbase = ((size_t)b * 8 + h);
    const unsigned short* Kh = Khi + kvbase * 2000 * 16;
    const unsigned short* Kl = Klo + kvbase * 2000 * 16;
    const unsigned short* Vh = Vhi + kvbase * 16 * 2000;
    const unsigned short* Vl = Vlo + kvbase * 16 * 2000;

    // staging indices
    int snr = tid >> 2, sj4 = (tid & 3) * 4;           // K: n-row, d-offset
    int svd = tid >> 4, svn = (tid & 15) * 4;          // V: d-row, n-offset

    for (int ch = s4 * 8; ch < s4 * 8 + 8; ++ch) {
        int n0 = ch * 64;
        __syncthreads();
        {
            uint2 zz; zz.x = 0; zz.y = 0;
            int n = n0 + snr;
            uint2 k0 = zz, k1 = zz;
            if (n < NN) {
                size_t off = ((size_t)n) * 16 + sj4;
                k0 = *(const uint2*)(Kh + off);
                k1 = *(const uint2*)(Kl + off);
            }
            *(uint2*)&Klds[0][snr][sj4] = k0;
            *(uint2*)&Klds[1][snr][sj4] = k1;
            int vn = n0 + svn;
            uint2 v0 = zz, v1 = zz;
            if (vn + 3 < NN) {
                size_t off = ((size_t)svd) * 2000 + vn;
                v0 = *(const uint2*)(Vh + off);
                v1 = *(const uint2*)(Vl + off);
            }
            *(uint2*)&Vlds[0][svd][svn] = v0;
            *(uint2*)&Vlds[1][svd][svn] = v1;
        }
        __syncthreads();

        unsigned long long wm0 = bb0[ch];
        unsigned long long wm1 = bb1[ch];

        // QK^T (transposed): S[nt][gt], D col=g, row n = 4*q3+r
        f32x4 S[4][2];
#pragma unroll
        for (int nt = 0; nt < 4; ++nt) {
            short8 kh, kl;
            if (q3 < 2) {
                kh = *(const short8*)&Klds[0][nt * 16 + l15][q3 * 8];
                kl = *(const short8*)&Klds[1][nt * 16 + l15][q3 * 8];
            } else { kh = z8; kl = z8; }
#pragma unroll
            for (int gt = 0; gt < 2; ++gt) {
                f32x4 c = {0.f, 0.f, 0.f, 0.f};
                c = __builtin_amdgcn_mfma_f32_16x16x32_bf16(kh, qf[gt][0], c, 0, 0, 0);
                c = __builtin_amdgcn_mfma_f32_16x16x32_bf16(kh, qf[gt][1], c, 0, 0, 0);
                c = __builtin_amdgcn_mfma_f32_16x16x32_bf16(kl, qf[gt][0], c, 0, 0, 0);
                S[nt][gt] = c;
            }
        }

        // mask + exp + split-pack P -> per-wave LDS
#pragma unroll
        for (int nt = 0; nt < 4; ++nt) {
#pragma unroll
            for (int gt = 0; gt < 2; ++gt) {
                unsigned long long wm = gt ? wm1 : wm0;
                float p[4];
#pragma unroll
                for (int r = 0; r < 4; ++r) {
                    int sh = nt * 16 + q3 * 4 + r;
                    float e = ((wm >> sh) & 1ull) ? __expf(S[nt][gt][r]) : 0.0f;
                    p[r] = e;
                    zacc[gt] += e;
                }
                unsigned short h4[4], l4[4];
#pragma unroll
                for (int r = 0; r < 4; ++r) {
                    h4[r] = bf16hi(p[r]); l4[r] = bf16hi(p[r] - bf16tof(h4[r]));
                }
                uint2 ph, pl;
                ph.x = (unsigned)h4[0] | ((unsigned)h4[1] << 16); ph.y = (unsigned)h4[2] | ((unsigned)h4[3] << 16);
                pl.x = (unsigned)l4[0] | ((unsigned)l4[1] << 16); pl.y = (unsigned)l4[2] | ((unsigned)l4[3] << 16);
                *(uint2*)&Plds[wv][0][gt * 16 + l15][nt * 16 + q3 * 4] = ph;
                *(uint2*)&Plds[wv][1][gt * 16 + l15][nt * 16 + q3 * 4] = pl;
            }
        }

        // PV: O^T += V^T · P   (A row=l15 -> d, k=8*q3+j -> n)
#pragma unroll
        for (int ks = 0; ks < 2; ++ks) {
            short8 vh = *(const short8*)&Vlds[0][l15][ks * 32 + q3 * 8];
            short8 vl = *(const short8*)&Vlds[1][l15][ks * 32 + q3 * 8];
#pragma unroll
            for (int gt = 0; gt < 2; ++gt) {
                short8 ph = *(const short8*)&Plds[wv][0][gt * 16 + l15][ks * 32 + q3 * 8];
                short8 pl = *(const short8*)&Plds[wv][1][gt * 16 + l15][ks * 32 + q3 * 8];
                Oacc[gt] = __builtin_amdgcn_mfma_f32_16x16x32_bf16(vh, ph, Oacc[gt], 0, 0, 0);
                Oacc[gt] = __builtin_amdgcn_mfma_f32_16x16x32_bf16(vh, pl, Oacc[gt], 0, 0, 0);
                Oacc[gt] = __builtin_amdgcn_mfma_f32_16x16x32_bf16(vl, ph, Oacc[gt], 0, 0, 0);
            }
        }
    }

    size_t obase = (((size_t)s4 * 64 + b) * 8 + h);
#pragma unroll
    for (int gt = 0; gt < 2; ++gt) {
        float z = zacc[gt];
        z += __shfl_xor(z, 16);
        z += __shfl_xor(z, 32);
        int g = wv * 32 + gt * 16 + l15;
        if (q3 == 0) Zpart[obase * 128 + g] = z;
#pragma unroll
        for (int r = 0; r < 4; ++r) {
            int d = q3 * 4 + r;
            Opart[(obase * 16 + d) * 128 + g] = Oacc[gt][r];
        }
    }
}

// ---- K7b: combine partials -> MHt[b][h*16+d][g] ----
__global__ __launch_bounds__(256) void k_ocomb(const float* Opart, const float* Zpart, float* MHt) {
    int bh = blockIdx.x;
    int b = bh >> 3, h = bh & 7;
    int tid = threadIdx.x;
    for (int e = tid; e < 2048; e += 256) {
        int d = e >> 7, g = e & 127;
        float z = 0.0f, o = 0.0f;
#pragma unroll
        for (int s = 0; s < 4; ++s) {
            z += Zpart[(((size_t)s * 64 + b) * 8 + h) * 128 + g];
            o += Opart[((((size_t)s * 64 + b) * 8 + h) * 16 + d) * 128 + g];
        }
        MHt[((size_t)b * 128 + h * 16 + d) * 128 + g] = o / z;
    }
}

// ---- K8: FQt[b][c][g] = (MH[b][g]@WcT + bc)*rsqrt(H) ----
__global__ __launch_bounds__(256) void k_fq(const float* MHt, const float* WT, const float* bcv, float* FQt) {
    int b = blockIdx.x;
    int tid = threadIdx.x, xq = tid & 15, yq = tid >> 4;
    __shared__ float Bl[128 * 132];
    for (int e = tid; e < 16384; e += 256) {
        int j = e >> 7, g = e & 127;
        Bl[j * 132 + g] = MHt[(size_t)b * 16384 + e];
    }
    __syncthreads();
    const float* Wc = WT + 6 * 16384;
    float acc[8][8] = {};
#pragma unroll 4
    for (int j = 0; j < 128; ++j) {
        const float4* Ar = (const float4*)(Wc + j * 128);
        float4 a0 = Ar[yq], a1 = Ar[16 + yq];
        const float4* Br = (const float4*)(Bl + j * 132);
        float4 b0 = Br[xq], b1 = Br[16 + xq];
        fma8x8(a0, a1, b0, b1, acc);
    }
    float4 bc0 = *(const float4*)(bcv + 4 * yq);
    float4 bc1 = *(const float4*)(bcv + 64 + 4 * yq);
    const float bcv8[8] = {bc0.x, bc0.y, bc0.z, bc0.w, bc1.x, bc1.y, bc1.z, bc1.w};
    const float sc = 0.08838834764831845f;
#pragma unroll
    for (int i = 0; i < 8; ++i) {
        int c = (i < 4) ? (4 * yq + i) : (64 + 4 * yq + (i - 4));
        float bci = bcv8[i];
        float* orow = FQt + ((size_t)b * 128 + c) * 128;
        *(float4*)(orow + 4 * xq) =
            make_float4((acc[i][0] + bci) * sc, (acc[i][1] + bci) * sc,
                        (acc[i][2] + bci) * sc, (acc[i][3] + bci) * sc);
        *(float4*)(orow + 64 + 4 * xq) =
            make_float4((acc[i][4] + bci) * sc, (acc[i][5] + bci) * sc,
                        (acc[i][6] + bci) * sc, (acc[i][7] + bci) * sc);
    }
}

// ---- K9: logits GEMM + tanh clip + masked exp ----
__global__ __launch_bounds__(256) void k_logits(const float* emb, const float* FQt, const unsigned long long* bits,
                         float* out, float* Zp) {
    int nt = blockIdx.x, b = blockIdx.y;
    int tid = threadIdx.x, xq = tid & 15, yq = tid >> 4;
    int n0 = nt * 128;
    __shared__ float Al[64 * 132];
    __shared__ float Bl[64 * 132];
    float acc[8][8] = {};
    for (int chh = 0; chh < 2; ++chh) {
        __syncthreads();
        for (int e = tid; e < 8192; e += 256) {
            int jl = e >> 7, g = e & 127;
            Al[jl * 132 + g] = FQt[((size_t)b * 128 + chh * 64 + jl) * 128 + g];
        }
        for (int e = tid; e < 8192; e += 256) {
            int jl = e & 63, r = e >> 6;
            int n = n0 + r;
            Bl[jl * 132 + r] = (n < NN) ? emb[((size_t)b * NN + n) * HH + chh * 64 + jl] : 0.0f;
        }
        __syncthreads();
#pragma unroll 4
        for (int jl = 0; jl < 64; ++jl) {
            const float4* Ar = (const float4*)(Al + jl * 132);
            float4 a0 = Ar[yq], a1 = Ar[16 + yq];
            const float4* Br = (const float4*)(Bl + jl * 132);
            float4 b0 = Br[xq], b1 = Br[16 + xq];
            fma8x8(a0, a1, b0, b1, acc);
        }
    }
    float psum[8];
    const unsigned long long* bb = bits + (size_t)b * 128 * 32;
#pragma unroll
    for (int i = 0; i < 8; ++i) {
        int g = (i < 4) ? (4 * yq + i) : (64 + 4 * yq + (i - 4));
        unsigned long long w0 = bb[g * 32 + nt * 2];
        unsigned long long w1 = bb[g * 32 + nt * 2 + 1];
        float* orow = out + ((size_t)b * 128 + g) * NN + n0;
        float ps = 0.0f;
        float pv[8];
#pragma unroll
        for (int k = 0; k < 8; ++k) {
            int nl = (k < 4) ? (4 * xq + k) : (64 + 4 * xq + (k - 4));
            unsigned long long w = (nl < 64) ? w0 : w1;
            int sh = nl & 63;
            float l = acc[i][k];
            float e2 = __expf(2.0f * l);
            float th = 1.0f - 2.0f / (e2 + 1.0f);
            float p = ((w >> sh) & 1ull) ? __expf(10.0f * th) : 0.0f;
            pv[k] = p;
            ps += p;
        }
        if (n0 + 4 * xq + 3 < NN)
            *(float4*)(orow + 4 * xq) = make_float4(pv[0], pv[1], pv[2], pv[3]);
        if (n0 + 64 + 4 * xq + 3 < NN)
            *(float4*)(orow + 64 + 4 * xq) = make_float4(pv[4], pv[5], pv[6], pv[7]);
        psum[i] = ps;
    }
#pragma unroll
    for (int i = 0; i < 8; ++i) {
#pragma unroll
        for (int m = 1; m <= 8; m <<= 1) psum[i] += __shfl_xor(psum[i], m);
    }
    if (xq == 0) {
#pragma unroll
        for (int i = 0; i < 8; ++i) {
            int g = (i < 4) ? (4 * yq + i) : (64 + 4 * yq + (i - 4));
            Zp[nt * 8192 + b * 128 + g] = psum[i];
        }
    }
}

// ---- K10: normalize probs ----
__global__ __launch_bounds__(256) void k_norm(const float* Zp, float* out) {
    int bg = blockIdx.x;
    __shared__ float invs;
    if (threadIdx.x == 0) {
        float s = 0.0f;
#pragma unroll
        for (int t = 0; t < 16; ++t) s += Zp[t * 8192 + bg];
        invs = 1.0f / s;
    }
    __syncthreads();
    float inv = invs;
    for (int n = threadIdx.x; n < NN; n += 256) out[(size_t)bg * NN + n] *= inv;
}

extern "C" void kernel_launch(void* const* d_in, const int* in_sizes, int n_in,
                              void* d_out, int out_size, void* d_ws, size_t ws_size,
                              hipStream_t stream) {
    const float* emb = (const float*)d_in[0];
    const float* mask = (const float*)d_in[1];
    const float* Wqg = (const float*)d_in[2];
    const float* Wqs = (const float*)d_in[3];
    const float* Wqt = (const float*)d_in[4];
    const float* Wql = (const float*)d_in[5];
    const float* Wk = (const float*)d_in[6];
    const float* Wv = (const float*)d_in[7];
    const float* Wc = (const float*)d_in[8];
    const float* bc = (const float*)d_in[9];
    const int* srcn = (const int*)d_in[10];
    const int* tgtn = (const int*)d_in[11];
    const int* lastn = (const int*)d_in[12];
    float* out = (float*)d_out;

    float* ws = (float*)d_ws;
    float* WT = ws;                               // 114688
    float* gpart = ws + 114688;                   // 131072
    float* qbase = ws + 245760;                   // 8192
    float* MHt = ws + 253952;                     // 1048576
    float* FQt = ws + 1302528;                    // 1048576
    float* Zp = ws + 2351104;                     // 131072
    unsigned short* Qhi = (unsigned short*)(ws + 2482176);   // 1048576 u16 = 524288 f
    unsigned short* Qlo = (unsigned short*)(ws + 3006464);   // 524288 f
    unsigned short* Khi = (unsigned short*)(ws + 3530752);   // 16384000 u16 = 8192000 f
    unsigned short* Klo = (unsigned short*)(ws + 11722752);
    unsigned short* Vhi = (unsigned short*)(ws + 19914752);
    unsigned short* Vlo = (unsigned short*)(ws + 28106752);
    unsigned long long* bits = (unsigned long long*)(ws + 36298752);  // 524288 f

    // flash partials live in d_out (overwritten later by k_logits)
    float* Opart = out;
    float* Zpart = out + 4194304;

    k_wt<<<7, 256, 0, stream>>>(Wqg, Wqs, Wqt, Wql, Wk, Wv, Wc, WT);
    k_maskbits<<<8192, 256, 0, stream>>>(mask, bits);
    k_gsum<<<dim3(16, 64), 128, 0, stream>>>(emb, gpart);
    k_kv<<<dim3(16, 64), 256, 0, stream>>>(emb, WT, Khi, Klo, Vhi, Vlo);
    k_qbase<<<64, 128, 0, stream>>>(emb, srcn, tgtn, gpart, WT, qbase);
    k_qlast<<<64, 256, 0, stream>>>(emb, lastn, WT, qbase, Qhi, Qlo);
    k_flash<<<2048, 256, 0, stream>>>(Khi, Klo, Vhi, Vlo, Qhi, Qlo, bits, Opart, Zpart);
    k_ocomb<<<512, 256, 0, stream>>>(Opart, Zpart, MHt);
    k_fq<<<64, 256, 0, stream>>>(MHt, WT, bc, FQt);
    k_logits<<<dim3(16, 64), 256, 0, stream>>>(emb, FQt, bits, out, Zp);
    k_norm<<<8192, 256, 0, stream>>>(Zp, out);
}

// Round 6
// 415.086 us; speedup vs baseline: 3.6526x; 1.1783x over previous
//
#include <hip/hip_runtime.h>
#include <hip/hip_bf16.h>

#define BB 64
#define NN 2000
#define GG 128
#define HH 128
#define NHEAD 8
#define HD 16

typedef __attribute__((ext_vector_type(8))) short short8;
typedef __attribute__((ext_vector_type(4))) float f32x4;

__device__ __forceinline__ unsigned short bf16hi(float f) {
    union { float f; unsigned u; } v; v.f = f;
    return (unsigned short)(v.u >> 16);
}
__device__ __forceinline__ float bf16tof(unsigned short h) {
    union { float f; unsigned u; } v; v.u = ((unsigned)h) << 16;
    return v.f;
}

__device__ __forceinline__ void fma8x8(const float4& a0, const float4& a1,
                                       const float4& b0, const float4& b1,
                                       float acc[8][8]) {
    const float av[8] = {a0.x, a0.y, a0.z, a0.w, a1.x, a1.y, a1.z, a1.w};
    const float bv[8] = {b0.x, b0.y, b0.z, b0.w, b1.x, b1.y, b1.z, b1.w};
#pragma unroll
    for (int i = 0; i < 8; ++i)
#pragma unroll
        for (int k = 0; k < 8; ++k) acc[i][k] += av[i] * bv[k];
}

// ---- K1: transpose Wqg,Wqs,Wqt,Wql,Wc (fp32) + convert Wk,Wv to bf16 hi/lo ----
__global__ __launch_bounds__(256) void k_wt(const float* w0, const float* w1, const float* w2,
                     const float* w3, const float* w4, const float* w5,
                     const float* w6, float* WT,
                     unsigned short* Wkhi, unsigned short* Wklo,
                     unsigned short* Wvhi, unsigned short* Wvlo) {
    int m = blockIdx.x;
    if (m >= 5) {
        const float* src = (m == 5) ? w4 : w5;
        unsigned short* dh = (m == 5) ? Wkhi : Wvhi;
        unsigned short* dl = (m == 5) ? Wklo : Wvlo;
        for (int e = threadIdx.x * 4; e < 16384; e += 1024) {
            float4 v = *(const float4*)(src + e);
            float fv[4] = {v.x, v.y, v.z, v.w};
            unsigned short h4[4], l4[4];
#pragma unroll
            for (int i = 0; i < 4; ++i) {
                h4[i] = bf16hi(fv[i]); l4[i] = bf16hi(fv[i] - bf16tof(h4[i]));
            }
            uint2 ph, pl;
            ph.x = h4[0] | (h4[1] << 16); ph.y = h4[2] | (h4[3] << 16);
            pl.x = l4[0] | (l4[1] << 16); pl.y = l4[2] | (l4[3] << 16);
            *(uint2*)(dh + e) = ph;
            *(uint2*)(dl + e) = pl;
        }
        return;
    }
    __shared__ float t[128 * 129];
    const float* src = (m == 0) ? w0 : (m == 1) ? w1 : (m == 2) ? w2 : (m == 3) ? w3 : w6;
    int slot = (m == 4) ? 6 : m;
    for (int e = threadIdx.x; e < 16384; e += 256) {
        int c = e >> 7, j = e & 127;
        t[c * 129 + j] = src[e];
    }
    __syncthreads();
    for (int e = threadIdx.x; e < 16384; e += 256) {
        int j = e >> 7, c = e & 127;
        WT[slot * 16384 + e] = t[c * 129 + j];
    }
}

// ---- K2: mask -> bitmask ----
__global__ __launch_bounds__(256) void k_maskbits(const float* mask, unsigned long long* bits) {
    int bg = blockIdx.x;
    int lane = threadIdx.x & 63;
    int wv = threadIdx.x >> 6;
    for (int w = wv; w < 32; w += 4) {
        int n = w * 64 + lane;
        bool keep = false;
        if (n < NN) keep = (mask[(size_t)bg * NN + n] == 0.0f);
        unsigned long long bal = __ballot(keep);
        if (lane == 0) bits[bg * 32 + w] = bal;
    }
}

// ---- K3: partial column sums of embeddings ----
__global__ __launch_bounds__(128) void k_gsum(const float* emb, float* gpart) {
    int ck = blockIdx.x, b = blockIdx.y, c = threadIdx.x;
    const float* p = emb + ((size_t)b * NN + ck * 125) * HH + c;
    float s = 0.0f;
#pragma unroll 5
    for (int r = 0; r < 125; ++r) s += p[(size_t)r * HH];
    gpart[ck * 8192 + b * 128 + c] = s;
}

// ---- K4: qbase ----
__global__ __launch_bounds__(128) void k_qbase(const float* emb, const int* srcn, const int* tgtn,
                        const float* gpart, const float* WT, float* qbase) {
    int b = blockIdx.x, c = threadIdx.x;
    __shared__ float ge[128], se[128], te[128];
    float s = 0.0f;
#pragma unroll
    for (int t = 0; t < 16; ++t) s += gpart[t * 8192 + b * 128 + c];
    ge[c] = s * (1.0f / 2000.0f);
    se[c] = emb[((size_t)b * NN + srcn[b]) * HH + c];
    te[c] = emb[((size_t)b * NN + tgtn[b]) * HH + c];
    __syncthreads();
    const float* Wg = WT;
    const float* Ws = WT + 16384;
    const float* Wt2 = WT + 32768;
    float acc = 0.0f;
#pragma unroll 4
    for (int j = 0; j < 128; ++j) {
        acc += ge[j] * Wg[j * 128 + c] + se[j] * Ws[j * 128 + c] + te[j] * Wt2[j * 128 + c];
    }
    qbase[b * 128 + c] = acc;
}

// ---- K5: Qhl[b][g][128] (bf16 hi/lo) = 0.25*(qbase + lastemb@WqlT) ----
__global__ __launch_bounds__(256) void k_qlast(const float* emb, const int* lastn, const float* WT,
                        const float* qbase, unsigned short* Qhi, unsigned short* Qlo) {
    int b = blockIdx.x;
    int tid = threadIdx.x, xq = tid & 15, yq = tid >> 4;
    __shared__ float Bl[128 * 132];
    for (int e = tid; e < 16384; e += 256) {
        int g = e >> 7, j = e & 127;
        Bl[j * 132 + g] = emb[((size_t)b * NN + lastn[b * 128 + g]) * HH + j];
    }
    __syncthreads();
    const float* Wql = WT + 3 * 16384;
    float acc[8][8] = {};
#pragma unroll 4
    for (int j = 0; j < 128; ++j) {
        const float4* Ar = (const float4*)(Wql + j * 128);
        float4 a0 = Ar[yq], a1 = Ar[16 + yq];
        const float4* Br = (const float4*)(Bl + j * 132);
        float4 b0 = Br[xq], b1 = Br[16 + xq];
        fma8x8(a0, a1, b0, b1, acc);
    }
    float4 qb0 = *(const float4*)(qbase + b * 128 + 4 * yq);
    float4 qb1 = *(const float4*)(qbase + b * 128 + 64 + 4 * yq);
    const float q0v[4] = {qb0.x, qb0.y, qb0.z, qb0.w};
    const float q1v[4] = {qb1.x, qb1.y, qb1.z, qb1.w};
#pragma unroll
    for (int k = 0; k < 8; ++k) {
        int g = (k < 4) ? (4 * xq + k) : (64 + 4 * xq + (k - 4));
        size_t base = ((size_t)b * 128 + g) * 128;
        unsigned short h4[4], l4[4];
#pragma unroll
        for (int i = 0; i < 4; ++i) {
            float f = (acc[i][k] + q0v[i]) * 0.25f;
            h4[i] = bf16hi(f); l4[i] = bf16hi(f - bf16tof(h4[i]));
        }
        uint2 ph, pl;
        ph.x = h4[0] | (h4[1] << 16); ph.y = h4[2] | (h4[3] << 16);
        pl.x = l4[0] | (l4[1] << 16); pl.y = l4[2] | (l4[3] << 16);
        *(uint2*)(Qhi + base + 4 * yq) = ph;
        *(uint2*)(Qlo + base + 4 * yq) = pl;
#pragma unroll
        for (int i = 0; i < 4; ++i) {
            float f = (acc[4 + i][k] + q1v[i]) * 0.25f;
            h4[i] = bf16hi(f); l4[i] = bf16hi(f - bf16tof(h4[i]));
        }
        ph.x = h4[0] | (h4[1] << 16); ph.y = h4[2] | (h4[3] << 16);
        pl.x = l4[0] | (l4[1] << 16); pl.y = l4[2] | (l4[3] << 16);
        *(uint2*)(Qhi + base + 64 + 4 * yq) = ph;
        *(uint2*)(Qlo + base + 64 + 4 * yq) = pl;
    }
}

// ---- shared: stage 128n x 128j emb tile as bf16 hi/lo into swizzled LDS ----
__device__ __forceinline__ void stage_emb(const float* emb, int b, int n0, int tid,
                                          unsigned short (*Eh)[128], unsigned short (*El)[128]) {
    int rr = tid >> 5, c4 = (tid & 31) * 4;
#pragma unroll
    for (int p = 0; p < 16; ++p) {
        int r = p * 8 + rr;
        int n = n0 + r;
        float4 v = make_float4(0.f, 0.f, 0.f, 0.f);
        if (n < NN) v = *(const float4*)(emb + ((size_t)b * NN + n) * HH + c4);
        float fv[4] = {v.x, v.y, v.z, v.w};
        unsigned short h4[4], l4[4];
#pragma unroll
        for (int i = 0; i < 4; ++i) {
            h4[i] = bf16hi(fv[i]); l4[i] = bf16hi(fv[i] - bf16tof(h4[i]));
        }
        uint2 ph, pl;
        ph.x = h4[0] | (h4[1] << 16); ph.y = h4[2] | (h4[3] << 16);
        pl.x = l4[0] | (l4[1] << 16); pl.y = l4[2] | (l4[3] << 16);
        int cs = c4 ^ ((r & 7) << 3);
        *(uint2*)&Eh[r][cs] = ph;
        *(uint2*)&El[r][cs] = pl;
    }
}

// ---- K6: K/V projections via split-bf16 MFMA ----
__global__ __launch_bounds__(256) void k_kv(const float* emb,
        const unsigned short* Wkhi, const unsigned short* Wklo,
        const unsigned short* Wvhi, const unsigned short* Wvlo,
        unsigned short* Khi, unsigned short* Klo,
        unsigned short* Vhi, unsigned short* Vlo) {
    int nt = blockIdx.x, b = blockIdx.y;
    int tid = threadIdx.x;
    int wv = tid >> 6, lane = tid & 63, l15 = lane & 15, q3 = lane >> 4;
    int n0 = nt * 128;
    __shared__ __align__(16) char ldsbuf[65536];
    unsigned short (*Eh)[128] = (unsigned short(*)[128])ldsbuf;
    unsigned short (*El)[128] = (unsigned short(*)[128])(ldsbuf + 32768);
    stage_emb(emb, b, n0, tid, Eh, El);
    __syncthreads();
    f32x4 aK[2][8], aV[2][8];
#pragma unroll
    for (int t = 0; t < 2; ++t)
#pragma unroll
        for (int ct = 0; ct < 8; ++ct) {
            aK[t][ct] = (f32x4){0.f, 0.f, 0.f, 0.f};
            aV[t][ct] = (f32x4){0.f, 0.f, 0.f, 0.f};
        }
#pragma unroll
    for (int ks = 0; ks < 4; ++ks) {
        short8 eh[2], el[2];
#pragma unroll
        for (int t = 0; t < 2; ++t) {
            int r = wv * 32 + t * 16 + l15;
            int cs = (ks * 32 + q3 * 8) ^ ((r & 7) << 3);
            eh[t] = *(const short8*)&Eh[r][cs];
            el[t] = *(const short8*)&El[r][cs];
        }
#pragma unroll
        for (int ct = 0; ct < 8; ++ct) {
            size_t woff = ((size_t)(ct * 16 + l15)) * 128 + ks * 32 + q3 * 8;
            short8 wkh = *(const short8*)(Wkhi + woff);
            short8 wkl = *(const short8*)(Wklo + woff);
            short8 wvh = *(const short8*)(Wvhi + woff);
            short8 wvl = *(const short8*)(Wvlo + woff);
#pragma unroll
            for (int t = 0; t < 2; ++t) {
                aK[t][ct] = __builtin_amdgcn_mfma_f32_16x16x32_bf16(eh[t], wkh, aK[t][ct], 0, 0, 0);
                aK[t][ct] = __builtin_amdgcn_mfma_f32_16x16x32_bf16(el[t], wkh, aK[t][ct], 0, 0, 0);
                aK[t][ct] = __builtin_amdgcn_mfma_f32_16x16x32_bf16(eh[t], wkl, aK[t][ct], 0, 0, 0);
                aV[t][ct] = __builtin_amdgcn_mfma_f32_16x16x32_bf16(eh[t], wvh, aV[t][ct], 0, 0, 0);
                aV[t][ct] = __builtin_amdgcn_mfma_f32_16x16x32_bf16(el[t], wvh, aV[t][ct], 0, 0, 0);
                aV[t][ct] = __builtin_amdgcn_mfma_f32_16x16x32_bf16(eh[t], wvl, aV[t][ct], 0, 0, 0);
            }
        }
    }
#pragma unroll
    for (int t = 0; t < 2; ++t) {
        int nb = n0 + wv * 32 + t * 16 + 4 * q3;
#pragma unroll
        for (int ct = 0; ct < 8; ++ct) {
            size_t kbase = ((size_t)b * 8 + ct) * 32000 + l15;
#pragma unroll
            for (int r = 0; r < 4; ++r) {
                int n = nb + r;
                if (n < NN) {
                    float f = aK[t][ct][r];
                    unsigned short hh = bf16hi(f);
                    Khi[kbase + (size_t)n * 16] = hh;
                    Klo[kbase + (size_t)n * 16] = bf16hi(f - bf16tof(hh));
                }
            }
            if (nb + 3 < NN) {
                unsigned short h4[4], l4[4];
#pragma unroll
                for (int r = 0; r < 4; ++r) {
                    float f = aV[t][ct][r];
                    h4[r] = bf16hi(f); l4[r] = bf16hi(f - bf16tof(h4[r]));
                }
                uint2 ph, pl;
                ph.x = h4[0] | (h4[1] << 16); ph.y = h4[2] | (h4[3] << 16);
                pl.x = l4[0] | (l4[1] << 16); pl.y = l4[2] | (l4[3] << 16);
                size_t vbase = (((size_t)b * 8 + ct) * 16 + l15) * 2000 + nb;
                *(uint2*)(Vhi + vbase) = ph;
                *(uint2*)(Vlo + vbase) = pl;
            }
        }
    }
}

// ---- K7: MFMA flash attention (split-bf16), 4-way n-split per (b,h) ----
__global__ __launch_bounds__(256) void k_flash(const unsigned short* Khi, const unsigned short* Klo,
                        const unsigned short* Vhi, const unsigned short* Vlo,
                        const unsigned short* Qhi, const unsigned short* Qlo,
                        const unsigned long long* bits, float* Opart, float* Zpart) {
    int bid = blockIdx.x;
    int s4 = bid & 3, h = (bid >> 2) & 7, b = bid >> 5;
    int tid = threadIdx.x;
    int wv = tid >> 6, lane = tid & 63, l15 = lane & 15, q3 = lane >> 4;

    __shared__ unsigned short Klds[2][64][24];
    __shared__ unsigned short Vlds[2][16][72];
    __shared__ unsigned short Plds[4][2][32][72];

    const short8 z8 = {0, 0, 0, 0, 0, 0, 0, 0};

    short8 qf[2][2];
#pragma unroll
    for (int gt = 0; gt < 2; ++gt) {
        int g = wv * 32 + gt * 16 + l15;
        if (q3 < 2) {
            size_t off = ((size_t)b * 128 + g) * 128 + h * 16 + q3 * 8;
            qf[gt][0] = *(const short8*)(Qhi + off);
            qf[gt][1] = *(const short8*)(Qlo + off);
        } else {
            qf[gt][0] = z8; qf[gt][1] = z8;
        }
    }

    f32x4 Oacc[2] = {{0.f, 0.f, 0.f, 0.f}, {0.f, 0.f, 0.f, 0.f}};
    float zacc[2] = {0.f, 0.f};

    const unsigned long long* bb0 = bits + (((size_t)b * 128 + wv * 32 + l15) * 32);
    const unsigned long long* bb1 = bb0 + 16 * 32;

    size_t kvbase = ((size_t)b * 8 + h);
    const unsigned short* Kh = Khi + kvbase * 2000 * 16;
    const unsigned short* Kl = Klo + kvbase * 2000 * 16;
    const unsigned short* Vh = Vhi + kvbase * 16 * 2000;
    const unsigned short* Vl = Vlo + kvbase * 16 * 2000;

    int snr = tid >> 2, sj4 = (tid & 3) * 4;
    int svd = tid >> 4, svn = (tid & 15) * 4;

    for (int ch = s4 * 8; ch < s4 * 8 + 8; ++ch) {
        int n0 = ch * 64;
        __syncthreads();
        {
            uint2 zz; zz.x = 0; zz.y = 0;
            int n = n0 + snr;
            uint2 k0 = zz, k1 = zz;
            if (n < NN) {
                size_t off = ((size_t)n) * 16 + sj4;
                k0 = *(const uint2*)(Kh + off);
                k1 = *(const uint2*)(Kl + off);
            }
            *(uint2*)&Klds[0][snr][sj4] = k0;
            *(uint2*)&Klds[1][snr][sj4] = k1;
            int vn = n0 + svn;
            uint2 v0 = zz, v1 = zz;
            if (vn + 3 < NN) {
                size_t off = ((size_t)svd) * 2000 + vn;
                v0 = *(const uint2*)(Vh + off);
                v1 = *(const uint2*)(Vl + off);
            }
            *(uint2*)&Vlds[0][svd][svn] = v0;
            *(uint2*)&Vlds[1][svd][svn] = v1;
        }
        __syncthreads();

        unsigned long long wm0 = bb0[ch];
        unsigned long long wm1 = bb1[ch];

        f32x4 S[4][2];
#pragma unroll
        for (int nt = 0; nt < 4; ++nt) {
            short8 kh, kl;
            if (q3 < 2) {
                kh = *(const short8*)&Klds[0][nt * 16 + l15][q3 * 8];
                kl = *(const short8*)&Klds[1][nt * 16 + l15][q3 * 8];
            } else { kh = z8; kl = z8; }
#pragma unroll
            for (int gt = 0; gt < 2; ++gt) {
                f32x4 c = {0.f, 0.f, 0.f, 0.f};
                c = __builtin_amdgcn_mfma_f32_16x16x32_bf16(kh, qf[gt][0], c, 0, 0, 0);
                c = __builtin_amdgcn_mfma_f32_16x16x32_bf16(kh, qf[gt][1], c, 0, 0, 0);
                c = __builtin_amdgcn_mfma_f32_16x16x32_bf16(kl, qf[gt][0], c, 0, 0, 0);
                S[nt][gt] = c;
            }
        }

#pragma unroll
        for (int nt = 0; nt < 4; ++nt) {
#pragma unroll
            for (int gt = 0; gt < 2; ++gt) {
                unsigned long long wm = gt ? wm1 : wm0;
                float p[4];
#pragma unroll
                for (int r = 0; r < 4; ++r) {
                    int sh = nt * 16 + q3 * 4 + r;
                    float e = ((wm >> sh) & 1ull) ? __expf(S[nt][gt][r]) : 0.0f;
                    p[r] = e;
                    zacc[gt] += e;
                }
                unsigned short h4[4], l4[4];
#pragma unroll
                for (int r = 0; r < 4; ++r) {
                    h4[r] = bf16hi(p[r]); l4[r] = bf16hi(p[r] - bf16tof(h4[r]));
                }
                uint2 ph, pl;
                ph.x = h4[0] | (h4[1] << 16); ph.y = h4[2] | (h4[3] << 16);
                pl.x = l4[0] | (l4[1] << 16); pl.y = l4[2] | (l4[3] << 16);
                *(uint2*)&Plds[wv][0][gt * 16 + l15][nt * 16 + q3 * 4] = ph;
                *(uint2*)&Plds[wv][1][gt * 16 + l15][nt * 16 + q3 * 4] = pl;
            }
        }

#pragma unroll
        for (int ks = 0; ks < 2; ++ks) {
            short8 vh = *(const short8*)&Vlds[0][l15][ks * 32 + q3 * 8];
            short8 vl = *(const short8*)&Vlds[1][l15][ks * 32 + q3 * 8];
#pragma unroll
            for (int gt = 0; gt < 2; ++gt) {
                short8 ph = *(const short8*)&Plds[wv][0][gt * 16 + l15][ks * 32 + q3 * 8];
                short8 pl = *(const short8*)&Plds[wv][1][gt * 16 + l15][ks * 32 + q3 * 8];
                Oacc[gt] = __builtin_amdgcn_mfma_f32_16x16x32_bf16(vh, ph, Oacc[gt], 0, 0, 0);
                Oacc[gt] = __builtin_amdgcn_mfma_f32_16x16x32_bf16(vh, pl, Oacc[gt], 0, 0, 0);
                Oacc[gt] = __builtin_amdgcn_mfma_f32_16x16x32_bf16(vl, ph, Oacc[gt], 0, 0, 0);
            }
        }
    }

    size_t obase = (((size_t)s4 * 64 + b) * 8 + h);
#pragma unroll
    for (int gt = 0; gt < 2; ++gt) {
        float z = zacc[gt];
        z += __shfl_xor(z, 16);
        z += __shfl_xor(z, 32);
        int g = wv * 32 + gt * 16 + l15;
        if (q3 == 0) Zpart[obase * 128 + g] = z;
#pragma unroll
        for (int r = 0; r < 4; ++r) {
            int d = q3 * 4 + r;
            Opart[(obase * 16 + d) * 128 + g] = Oacc[gt][r];
        }
    }
}

// ---- K7b: combine partials -> MHt[b][h*16+d][g] ----
__global__ __launch_bounds__(256) void k_ocomb(const float* Opart, const float* Zpart, float* MHt) {
    int bh = blockIdx.x;
    int b = bh >> 3, h = bh & 7;
    int tid = threadIdx.x;
    for (int e = tid; e < 2048; e += 256) {
        int d = e >> 7, g = e & 127;
        float z = 0.0f, o = 0.0f;
#pragma unroll
        for (int s = 0; s < 4; ++s) {
            z += Zpart[(((size_t)s * 64 + b) * 8 + h) * 128 + g];
            o += Opart[((((size_t)s * 64 + b) * 8 + h) * 16 + d) * 128 + g];
        }
        MHt[((size_t)b * 128 + h * 16 + d) * 128 + g] = o / z;
    }
}

// ---- K8: FQhl[b][g][c] (bf16 hi/lo) = (MH[b][g]@WcT + bc)*rsqrt(H) ----
__global__ __launch_bounds__(256) void k_fq(const float* MHt, const float* WT, const float* bcv,
                                            unsigned short* FQhi, unsigned short* FQlo) {
    int b = blockIdx.x;
    int tid = threadIdx.x, xq = tid & 15, yq = tid >> 4;
    __shared__ float Bl[128 * 132];
    for (int e = tid; e < 16384; e += 256) {
        int j = e >> 7, g = e & 127;
        Bl[j * 132 + g] = MHt[(size_t)b * 16384 + e];
    }
    __syncthreads();
    const float* Wc = WT + 6 * 16384;
    float acc[8][8] = {};
#pragma unroll 4
    for (int j = 0; j < 128; ++j) {
        const float4* Ar = (const float4*)(Wc + j * 128);
        float4 a0 = Ar[yq], a1 = Ar[16 + yq];
        const float4* Br = (const float4*)(Bl + j * 132);
        float4 b0 = Br[xq], b1 = Br[16 + xq];
        fma8x8(a0, a1, b0, b1, acc);
    }
    float4 bc0 = *(const float4*)(bcv + 4 * yq);
    float4 bc1 = *(const float4*)(bcv + 64 + 4 * yq);
    const float bcv8[8] = {bc0.x, bc0.y, bc0.z, bc0.w, bc1.x, bc1.y, bc1.z, bc1.w};
    const float sc = 0.08838834764831845f;  // 1/sqrt(128)
#pragma unroll
    for (int k = 0; k < 8; ++k) {
        int g = (k < 4) ? (4 * xq + k) : (64 + 4 * xq + (k - 4));
        size_t base = ((size_t)b * 128 + g) * 128;
        unsigned short h4[4], l4[4];
#pragma unroll
        for (int i = 0; i < 4; ++i) {
            float f = (acc[i][k] + bcv8[i]) * sc;
            h4[i] = bf16hi(f); l4[i] = bf16hi(f - bf16tof(h4[i]));
        }
        uint2 ph, pl;
        ph.x = h4[0] | (h4[1] << 16); ph.y = h4[2] | (h4[3] << 16);
        pl.x = l4[0] | (l4[1] << 16); pl.y = l4[2] | (l4[3] << 16);
        *(uint2*)(FQhi + base + 4 * yq) = ph;
        *(uint2*)(FQlo + base + 4 * yq) = pl;
#pragma unroll
        for (int i = 0; i < 4; ++i) {
            float f = (acc[4 + i][k] + bcv8[4 + i]) * sc;
            h4[i] = bf16hi(f); l4[i] = bf16hi(f - bf16tof(h4[i]));
        }
        ph.x = h4[0] | (h4[1] << 16); ph.y = h4[2] | (h4[3] << 16);
        pl.x = l4[0] | (l4[1] << 16); pl.y = l4[2] | (l4[3] << 16);
        *(uint2*)(FQhi + base + 64 + 4 * yq) = ph;
        *(uint2*)(FQlo + base + 64 + 4 * yq) = pl;
    }
}

// ---- K9: logits via split-bf16 MFMA + tanh clip + masked exp ----
__global__ __launch_bounds__(256) void k_logits(const float* emb,
        const unsigned short* FQhi, const unsigned short* FQlo,
        const unsigned long long* bits, float* out, float* Zp) {
    int nt = blockIdx.x, b = blockIdx.y;
    int tid = threadIdx.x;
    int wv = tid >> 6, lane = tid & 63, l15 = lane & 15, q3 = lane >> 4;
    int n0 = nt * 128;
    __shared__ __align__(16) char ldsbuf[65536];
    unsigned short (*Eh)[128] = (unsigned short(*)[128])ldsbuf;
    unsigned short (*El)[128] = (unsigned short(*)[128])(ldsbuf + 32768);
    float (*Pl)[128] = (float(*)[128])ldsbuf;
    stage_emb(emb, b, n0, tid, Eh, El);
    __syncthreads();
    f32x4 acc[2][8];
#pragma unroll
    for (int t = 0; t < 2; ++t)
#pragma unroll
        for (int gt = 0; gt < 8; ++gt) acc[t][gt] = (f32x4){0.f, 0.f, 0.f, 0.f};
#pragma unroll
    for (int ks = 0; ks < 4; ++ks) {
        short8 beh[2], bel[2];
#pragma unroll
        for (int t = 0; t < 2; ++t) {
            int r = wv * 32 + t * 16 + l15;
            int cs = (ks * 32 + q3 * 8) ^ ((r & 7) << 3);
            beh[t] = *(const short8*)&Eh[r][cs];
            bel[t] = *(const short8*)&El[r][cs];
        }
#pragma unroll
        for (int gt = 0; gt < 8; ++gt) {
            size_t foff = ((size_t)b * 128 + gt * 16 + l15) * 128 + ks * 32 + q3 * 8;
            short8 fh = *(const short8*)(FQhi + foff);
            short8 fl = *(const short8*)(FQlo + foff);
#pragma unroll
            for (int t = 0; t < 2; ++t) {
                acc[t][gt] = __builtin_amdgcn_mfma_f32_16x16x32_bf16(fh, beh[t], acc[t][gt], 0, 0, 0);
                acc[t][gt] = __builtin_amdgcn_mfma_f32_16x16x32_bf16(fl, beh[t], acc[t][gt], 0, 0, 0);
                acc[t][gt] = __builtin_amdgcn_mfma_f32_16x16x32_bf16(fh, bel[t], acc[t][gt], 0, 0, 0);
            }
        }
    }
    __syncthreads();  // LDS reuse: Eh/El -> Pl
    float psum[8][4];
#pragma unroll
    for (int gt = 0; gt < 8; ++gt)
#pragma unroll
        for (int r = 0; r < 4; ++r) psum[gt][r] = 0.f;
    const unsigned long long* bb = bits + (size_t)b * 128 * 32;
#pragma unroll
    for (int t = 0; t < 2; ++t) {
        int nl = wv * 32 + t * 16 + l15;
        int wordofs = nt * 2 + ((wv * 32 + t * 16) >> 6);
        int sh = (n0 + nl) & 63;
#pragma unroll
        for (int gt = 0; gt < 8; ++gt) {
#pragma unroll
            for (int r = 0; r < 4; ++r) {
                int g = gt * 16 + 4 * q3 + r;
                unsigned long long wm = bb[g * 32 + wordofs];
                float l = acc[t][gt][r];
                float e2 = __expf(2.0f * l);
                float th = 1.0f - 2.0f / (e2 + 1.0f);
                float p = ((wm >> sh) & 1ull) ? __expf(10.0f * th) : 0.0f;
                psum[gt][r] += p;
                Pl[g][nl ^ ((g & 7) << 2)] = p;
            }
        }
    }
#pragma unroll
    for (int gt = 0; gt < 8; ++gt)
#pragma unroll
        for (int r = 0; r < 4; ++r) {
            float v = psum[gt][r];
            v += __shfl_xor(v, 1); v += __shfl_xor(v, 2);
            v += __shfl_xor(v, 4); v += __shfl_xor(v, 8);
            if (l15 == 0) {
                int g = gt * 16 + 4 * q3 + r;
                Zp[((size_t)(nt * 4 + wv)) * 8192 + b * 128 + g] = v;
            }
        }
    __syncthreads();
    for (int e = tid; e < 4096; e += 256) {
        int g = e >> 5, c4 = (e & 31) * 4;
        int n = n0 + c4;
        if (n + 3 < NN) {
            *(float4*)(out + ((size_t)b * 128 + g) * NN + n) =
                *(float4*)&Pl[g][c4 ^ ((g & 7) << 2)];
        }
    }
}

// ---- K10: normalize probs (64 partial-sum slots) ----
__global__ __launch_bounds__(256) void k_norm(const float* Zp, float* out) {
    int bg = blockIdx.x;
    __shared__ float invs;
    if (threadIdx.x == 0) {
        float s = 0.0f;
#pragma unroll
        for (int t = 0; t < 64; ++t) s += Zp[(size_t)t * 8192 + bg];
        invs = 1.0f / s;
    }
    __syncthreads();
    float inv = invs;
    for (int n = threadIdx.x; n < NN; n += 256) out[(size_t)bg * NN + n] *= inv;
}

extern "C" void kernel_launch(void* const* d_in, const int* in_sizes, int n_in,
                              void* d_out, int out_size, void* d_ws, size_t ws_size,
                              hipStream_t stream) {
    const float* emb = (const float*)d_in[0];
    const float* mask = (const float*)d_in[1];
    const float* Wqg = (const float*)d_in[2];
    const float* Wqs = (const float*)d_in[3];
    const float* Wqt = (const float*)d_in[4];
    const float* Wql = (const float*)d_in[5];
    const float* Wk = (const float*)d_in[6];
    const float* Wv = (const float*)d_in[7];
    const float* Wc = (const float*)d_in[8];
    const float* bc = (const float*)d_in[9];
    const int* srcn = (const int*)d_in[10];
    const int* tgtn = (const int*)d_in[11];
    const int* lastn = (const int*)d_in[12];
    float* out = (float*)d_out;

    // ---- workspace map (float offsets). K/V arrays are 8,192,000 floats
    // (16,384,000 u16) EACH — round-5 bug was sizing these 4x too small,
    // letting Khi/Klo writes trash Vhi/Vlo and the mask bits. ----
    float* ws = (float*)d_ws;
    float* WT = ws;                                   // [0, 114688)
    unsigned short* Wkhi = (unsigned short*)(WT + 4 * 16384);   // slots 4-5 as bf16
    unsigned short* Wklo = Wkhi + 16384;
    unsigned short* Wvhi = Wklo + 16384;
    unsigned short* Wvlo = Wvhi + 16384;
    float* gpart = ws + 114688;                       // [114688, 245760)
    float* qbase = ws + 245760;                       // [245760, 253952)
    float* MHt = ws + 253952;                         // [253952, 1302528)
    unsigned short* FQhi = (unsigned short*)(ws + 1302528);     // [1302528, 2351104)
    unsigned short* FQlo = FQhi + 1048576;
    float* Zp = ws + 2351104;                         // [2351104, 2875392)
    unsigned short* Khi = (unsigned short*)(ws + 2875392);      // [2875392, 11067392)
    unsigned short* Klo = (unsigned short*)(ws + 11067392);     // [11067392, 19259392)
    unsigned short* Vhi = (unsigned short*)(ws + 19259392);     // [19259392, 27451392)
    unsigned short* Vlo = (unsigned short*)(ws + 27451392);     // [27451392, 35643392)
    unsigned long long* bits = (unsigned long long*)(ws + 35643392);  // [35643392, 36167680)

    // flash partials + Q live in d_out (all consumed before k_logits writes it)
    float* Opart = out;                               // [0, 4194304)
    float* Zpart = out + 4194304;                     // [4194304, 4456448)
    unsigned short* Qhi = (unsigned short*)(out + 4456448);     // [4456448, 4980736)
    unsigned short* Qlo = Qhi + 1048576;                        // [4980736, 5505024)

    k_wt<<<7, 256, 0, stream>>>(Wqg, Wqs, Wqt, Wql, Wk, Wv, Wc, WT, Wkhi, Wklo, Wvhi, Wvlo);
    k_maskbits<<<8192, 256, 0, stream>>>(mask, bits);
    k_gsum<<<dim3(16, 64), 128, 0, stream>>>(emb, gpart);
    k_kv<<<dim3(16, 64), 256, 0, stream>>>(emb, Wkhi, Wklo, Wvhi, Wvlo, Khi, Klo, Vhi, Vlo);
    k_qbase<<<64, 128, 0, stream>>>(emb, srcn, tgtn, gpart, WT, qbase);
    k_qlast<<<64, 256, 0, stream>>>(emb, lastn, WT, qbase, Qhi, Qlo);
    k_flash<<<2048, 256, 0, stream>>>(Khi, Klo, Vhi, Vlo, Qhi, Qlo, bits, Opart, Zpart);
    k_ocomb<<<512, 256, 0, stream>>>(Opart, Zpart, MHt);
    k_fq<<<64, 256, 0, stream>>>(MHt, WT, bc, FQhi, FQlo);
    k_logits<<<dim3(16, 64), 256, 0, stream>>>(emb, FQhi, FQlo, bits, out, Zp);
    k_norm<<<8192, 256, 0, stream>>>(Zp, out);
}